// Round 3
// baseline (2739.441 us; speedup 1.0000x reference)
//
#include <hip/hip_runtime.h>
#include <hip/hip_bf16.h>

#define B_ 256
#define T_ 128
#define D_ 512
#define H_ 1024
#define FC_ 1024
#define A_ 32
#define NWG_ 256

typedef short bf16x8 __attribute__((ext_vector_type(8)));
typedef float f32x4 __attribute__((ext_vector_type(4)));
typedef unsigned long long ull;
typedef ull ullx2 __attribute__((ext_vector_type(2)));

__device__ __forceinline__ float bf2f(unsigned short u) {
  return __uint_as_float(((unsigned)u) << 16);
}
// round-to-nearest-even fp32 -> bf16
__device__ __forceinline__ unsigned short f2bf(float x) {
  unsigned u = __float_as_uint(x);
  u = u + 0x7fffu + ((u >> 16) & 1u);
  return (unsigned short)(u >> 16);
}
__device__ __forceinline__ void unpack8(uint4 v, float* f) {
  f[0] = bf2f(v.x & 0xffff); f[1] = bf2f(v.x >> 16);
  f[2] = bf2f(v.y & 0xffff); f[3] = bf2f(v.y >> 16);
  f[4] = bf2f(v.z & 0xffff); f[5] = bf2f(v.z >> 16);
  f[6] = bf2f(v.w & 0xffff); f[7] = bf2f(v.w >> 16);
}
__device__ __forceinline__ uint4 pack8(const float* f) {
  uint4 v;
  v.x = (unsigned)f2bf(f[0]) | ((unsigned)f2bf(f[1]) << 16);
  v.y = (unsigned)f2bf(f[2]) | ((unsigned)f2bf(f[3]) << 16);
  v.z = (unsigned)f2bf(f[4]) | ((unsigned)f2bf(f[5]) << 16);
  v.w = (unsigned)f2bf(f[6]) | ((unsigned)f2bf(f[7]) << 16);
  return v;
}

// ------------- dtype probe: bf16 inputs -> flag 0, fp32 inputs -> flag 1 -----
__global__ __launch_bounds__(256) void detect_kernel(
    const unsigned short* __restrict__ obs, int* __restrict__ flag)
{
  __shared__ int cnt;
  if (threadIdx.x == 0) cnt = 0;
  __syncthreads();
  int c = 0;
  for (int i = threadIdx.x; i < 8192; i += 256) {
    unsigned e = (obs[i] >> 7) & 0xffu;  // bf16 exponent field
    if (e >= 0x86u) c++;
  }
  atomicAdd(&cnt, c);
  __syncthreads();
  if (threadIdx.x == 0) *flag = (cnt >= 64) ? 1 : 0;
}

// ------------- canonicalize 14 float tensors to bf16 workspace copies -------
struct CanonArgs {
  const void* src[14];
  unsigned short* dst[14];
  int ofs[15];  // cumulative element offsets (all multiples of 8)
};
__global__ __launch_bounds__(256) void canon_kernel(CanonArgs a,
                                                    const int* __restrict__ flag)
{
  const int fl = *flag;
  const int i0 = (blockIdx.x * 256 + threadIdx.x) * 8;
  int t = 0;
  while (t < 14 && i0 >= a.ofs[t + 1]) t++;
  if (t >= 14) return;
  const int local = i0 - a.ofs[t];
  unsigned short* d = a.dst[t] + local;
  if (fl) {
    const float* s = (const float*)a.src[t] + local;
    #pragma unroll
    for (int e = 0; e < 8; e++) d[e] = f2bf(s[e]);
  } else {
    const unsigned short* s = (const unsigned short*)a.src[t] + local;
    #pragma unroll
    for (int e = 0; e < 8; e++) d[e] = s[e];
  }
}

// ---------------- LayerNorm: one wave per row of D=512 (chunked over t) ------
__global__ __launch_bounds__(256) void ln_kernel(
    const void* __restrict__ obs,
    const unsigned short* __restrict__ gamma_,
    const unsigned short* __restrict__ beta_,
    unsigned short* __restrict__ xn, int t0, int tcShift,
    const int* __restrict__ flag)
{
  const int fl = *flag;
  const int lane = threadIdx.x & 63;
  const int rloc = blockIdx.x * 4 + (threadIdx.x >> 6);
  const int b  = rloc >> tcShift;
  const int tl = rloc & ((1 << tcShift) - 1);
  const int grow = b * T_ + t0 + tl;
  float f[8];
  if (fl) {
    const float* of = (const float*)obs + (size_t)grow * D_ + lane * 8;
    const float4 v0 = *(const float4*)of;
    const float4 v1 = *(const float4*)(of + 4);
    f[0] = v0.x; f[1] = v0.y; f[2] = v0.z; f[3] = v0.w;
    f[4] = v1.x; f[5] = v1.y; f[6] = v1.z; f[7] = v1.w;
  } else {
    uint4 v = *(const uint4*)((const unsigned short*)obs + (size_t)grow * D_ + lane * 8);
    unpack8(v, f);
  }
  float s = 0.f, ss = 0.f;
  #pragma unroll
  for (int i = 0; i < 8; i++) { s += f[i]; ss += f[i] * f[i]; }
  #pragma unroll
  for (int off = 32; off > 0; off >>= 1) {
    s  += __shfl_xor(s,  off, 64);
    ss += __shfl_xor(ss, off, 64);
  }
  const float mu  = s * (1.0f / D_);
  const float var = ss * (1.0f / D_) - mu * mu;
  const float inv = rsqrtf(var + 1e-5f);
  float g[8], b8[8];
  unpack8(*(const uint4*)(gamma_ + lane * 8), g);
  unpack8(*(const uint4*)(beta_  + lane * 8), b8);
  float o[8];
  #pragma unroll
  for (int i = 0; i < 8; i++) o[i] = (f[i] - mu) * inv * g[i] + b8[i];
  *(uint4*)(xn + (size_t)rloc * D_ + lane * 8) = pack8(o);
}

// ------------- generic TN GEMM: C[M,N] = A[M,K] * B[N,K]^T + bias -------------
// m97 structure: 128x128 tile, BK=32, linear LDS, global_load_lds width=16,
// 2-barrier K-loop. Staging never touches VGPRs.
__global__ __launch_bounds__(256) void gemm_tn(
    const unsigned short* __restrict__ A, const unsigned short* __restrict__ Bm,
    const unsigned short* __restrict__ bias, unsigned short* __restrict__ C,
    int M, int N, int K, int relu)
{
  __shared__ short As[128 * 32];   // [row][k] linear, 8KB
  __shared__ short Bs[128 * 32];
  const int tid  = threadIdx.x;
  const int wave = tid >> 6, lane = tid & 63;
  const int quad = lane >> 4, l15 = lane & 15;
  const int m0 = blockIdx.y * 128, n0 = blockIdx.x * 128;
  const int wm = (wave >> 1) * 64, wn = (wave & 1) * 64;
  const int srow = tid >> 2;          // 0..63
  const int skc  = (tid & 3) * 8;     // shorts
  const size_t aoff0 = (size_t)(m0 + srow) * K + skc;
  const size_t aoff1 = (size_t)(m0 + 64 + srow) * K + skc;
  const size_t boff0 = (size_t)(n0 + srow) * K + skc;
  const size_t boff1 = (size_t)(n0 + 64 + srow) * K + skc;
  const int lb0 = wave * 512;          // shorts
  const int lb1 = 2048 + wave * 512;
  f32x4 acc[4][4] = {};
  for (int k0 = 0; k0 < K; k0 += 32) {
    __syncthreads();
    __builtin_amdgcn_global_load_lds(
        (const __attribute__((address_space(1))) unsigned*)(A + aoff0 + k0),
        (__attribute__((address_space(3))) unsigned*)&As[lb0], 16, 0, 0);
    __builtin_amdgcn_global_load_lds(
        (const __attribute__((address_space(1))) unsigned*)(A + aoff1 + k0),
        (__attribute__((address_space(3))) unsigned*)&As[lb1], 16, 0, 0);
    __builtin_amdgcn_global_load_lds(
        (const __attribute__((address_space(1))) unsigned*)(Bm + boff0 + k0),
        (__attribute__((address_space(3))) unsigned*)&Bs[lb0], 16, 0, 0);
    __builtin_amdgcn_global_load_lds(
        (const __attribute__((address_space(1))) unsigned*)(Bm + boff1 + k0),
        (__attribute__((address_space(3))) unsigned*)&Bs[lb1], 16, 0, 0);
    __syncthreads();  // compiler drains vmcnt before barrier
    bf16x8 af[4], bfv[4];
    #pragma unroll
    for (int i = 0; i < 4; i++) af[i]  = *(const bf16x8*)&As[(wm + i * 16 + l15) * 32 + quad * 8];
    #pragma unroll
    for (int j = 0; j < 4; j++) bfv[j] = *(const bf16x8*)&Bs[(wn + j * 16 + l15) * 32 + quad * 8];
    #pragma unroll
    for (int i = 0; i < 4; i++)
      #pragma unroll
      for (int j = 0; j < 4; j++)
        acc[i][j] = __builtin_amdgcn_mfma_f32_16x16x32_bf16(af[i], bfv[j], acc[i][j], 0, 0, 0);
  }
  #pragma unroll
  for (int j = 0; j < 4; j++) {
    const int col = n0 + wn + j * 16 + l15;
    const float bj = bias ? bf2f(bias[col]) : 0.0f;
    #pragma unroll
    for (int i = 0; i < 4; i++) {
      const int row = m0 + wm + i * 16 + quad * 4;
      #pragma unroll
      for (int r = 0; r < 4; r++) {
        float v = acc[i][j][r] + bj;
        if (relu) v = fmaxf(v, 0.0f);
        C[(size_t)(row + r) * N + col] = f2bf(v);
      }
    }
  }
}

// ---------------- persistent GRU scan (acquire-fence LLC protocol) -----------
// 256 WGs (1/CU). WG = (bb,jb): bb owns 64 batches, jb owns 16 cols x 3 gates.
// W_hh slice (96KB) + starts bitmask in LDS once. h fp32 in registers.
// v4 changes vs v1/v3:
//  * amdgpu_waves_per_eu(1,1): pins the VGPR budget at 512 (occupancy is 1
//    wave/SIMD anyway from 100KB LDS). The full step h-tile (32 x uint4 =
//    128 VGPRs) now lives in registers; v2/v3's load re-serialization was the
//    compiler's ~132-reg pressure target, not a structural necessity.
//  * Exchange reads: single-lane poll of a per-bb-group atomicAdd counter
//    (sum >= 64*t  <=>  all 64 producers completed step t-1), then ONE agent
//    acquire fence (buffer_inv) per step, then PLAIN uint4 loads. Producer
//    stores are agent-scope write-through (LLC-visible before the counter
//    bump), so post-invalidate plain loads are fresh; the 64x-redundant
//    reads within an XCD become L2 hits (LLC traffic /8, 16B/instr).
//  * All stores that could sit dirty in L2 while fences fire (hall, hf)
//    are agent-scope write-through too.
__global__ __launch_bounds__(256, 1) __attribute__((amdgpu_waves_per_eu(1, 1)))
void gru_scan(
    const unsigned short* __restrict__ xg,   // chunk-local [B][Tc][3H]
    const int* __restrict__ starts,
    const unsigned short* __restrict__ Whh,
    const unsigned short* __restrict__ bhh,
    float* __restrict__ hf,                  // [B][H] fp32 master
    ull* __restrict__ hb0,                   // bf16 mirror ping
    ull* __restrict__ hb1,                   // bf16 mirror pong
    unsigned short* __restrict__ hall,       // [B][Tc][H] bf16
    int t0, int Tc,
    int* __restrict__ flags)                 // per-bb step counters, 128B apart
{
  __shared__ short Ws[3 * 16 * 1032];   // 99 KB: [g][jj][k] stride 1032
  __shared__ unsigned sbits[64][4];     // starts bitmask: 64 rows x 128 bits
  const int tid  = threadIdx.x;
  const int wg   = blockIdx.x;
  const int jb   = wg & 63, bb = wg >> 6;
  const int j0   = jb * 16, b0 = bb * 64;
  const int wave = tid >> 6, lane = tid & 63;
  const int quad = lane >> 4, l15 = lane & 15;

  // one-time: W_hh slice -> LDS (48 rows x 1024 k)
  for (int c = tid; c < 48 * 128; c += 256) {
    const int row = c >> 7;          // g*16 + jj
    const int kc  = (c & 127) * 8;
    const int g = row >> 4, jj = row & 15;
    *(uint4*)&Ws[row * 1032 + kc] =
        *(const uint4*)(Whh + (size_t)(g * H_ + j0 + jj) * H_ + kc);
  }
  // one-time: starts -> bitmask
  for (int c = tid; c < 64 * 4; c += 256) {
    const int row = c >> 2, w = c & 3;
    unsigned m = 0;
    #pragma unroll
    for (int bi = 0; bi < 32; bi++)
      m |= (starts[(b0 + row) * T_ + w * 32 + bi] ? 1u : 0u) << bi;
    sbits[row][w] = m;
  }
  const float br = bf2f(bhh[j0 + l15]);
  const float bz = bf2f(bhh[H_ + j0 + l15]);
  const float bn = bf2f(bhh[2 * H_ + j0 + l15]);
  const int col = j0 + l15;

  // register-resident fp32 h: 4 owned slots (rows r0..r0+3, col)
  const int r0 = wave * 16 + quad * 4;
  float hreg[4];
  #pragma unroll
  for (int r = 0; r < 4; r++)
    hreg[r] = hf[(size_t)(b0 + r0 + r) * H_ + col];

  // A-operand row for this lane; 16B fragment per k-window at [j*4 + quad]
  const int arow = wave * 16 + l15;
  const uint4* h0v = (const uint4*)hb0 + (((size_t)(b0 + arow) * H_) >> 3) + quad;
  const uint4* h1v = (const uint4*)hb1 + (((size_t)(b0 + arow) * H_) >> 3) + quad;
  const short* wsb = &Ws[l15 * 1032 + quad * 8];
  int* cnt = &flags[bb * 32];

  __syncthreads();  // Ws / sbits ready

  for (int tl = 0; tl < Tc; tl++) {
    const int t = t0 + tl;
    unsigned* hout_u = (unsigned*)((t & 1) ? hb0 : hb1);
    const unsigned tw = (unsigned)(t >> 5), tb = (unsigned)(t & 31);

    // xg for this step (independent of h; overlaps the poll)
    float xr[4], xz[4], xnv[4];
    #pragma unroll
    for (int r = 0; r < 4; r++) {
      const size_t xrow = ((size_t)(b0 + r0 + r) * Tc + tl) * (3 * H_);
      xr[r]  = bf2f(xg[xrow + col]);
      xz[r]  = bf2f(xg[xrow + H_ + col]);
      xnv[r] = bf2f(xg[xrow + 2 * H_ + col]);
    }

    // wait: all 64 producers of this bb-group completed step t-1
    if (tid == 0) {
      const int tgt = 64 * t;
      while (__hip_atomic_load(cnt, __ATOMIC_RELAXED,
                               __HIP_MEMORY_SCOPE_AGENT) < tgt)
        __builtin_amdgcn_s_sleep(1);
    }
    __syncthreads();
    // acquire: invalidate L1/L2 so plain loads see producers' LLC data
    __builtin_amdgcn_fence(__ATOMIC_ACQUIRE, "agent");
    __builtin_amdgcn_sched_barrier(0);

    // full step h-tile into registers (32 x 16B plain loads, L2-shareable)
    uint4 hv[32];
    {
      const uint4* hrow = (t & 1) ? h1v : h0v;
      #pragma unroll
      for (int j = 0; j < 32; j++) hv[j] = hrow[j * 4];
    }
    __builtin_amdgcn_sched_barrier(0);

    // episode-start mask for this lane's A row
    const ull keep = ((sbits[arow][tw] >> tb) & 1u) ? 0ull : ~0ull;

    f32x4 acc[3] = {};
    #pragma unroll
    for (int j = 0; j < 32; j++) {
      ullx2 u2 = __builtin_bit_cast(ullx2, hv[j]);
      u2.x &= keep;
      u2.y &= keep;
      const bf16x8 a = __builtin_bit_cast(bf16x8, u2);
      acc[0] = __builtin_amdgcn_mfma_f32_16x16x32_bf16(
          a, *(const bf16x8*)(wsb + 0 * 16512 + j * 32), acc[0], 0, 0, 0);
      acc[1] = __builtin_amdgcn_mfma_f32_16x16x32_bf16(
          a, *(const bf16x8*)(wsb + 1 * 16512 + j * 32), acc[1], 0, 0, 0);
      acc[2] = __builtin_amdgcn_mfma_f32_16x16x32_bf16(
          a, *(const bf16x8*)(wsb + 2 * 16512 + j * 32), acc[2], 0, 0, 0);
    }

    // epilogue: gate math in registers; pack col pairs; write-through stores
    #pragma unroll
    for (int r = 0; r < 4; r++) {
      const int lrow = r0 + r;
      const int b = b0 + lrow;
      const float kb = ((sbits[lrow][tw] >> tb) & 1u) ? 0.0f : 1.0f;
      const float hr = acc[0][r] + br;
      const float hz = acc[1][r] + bz;
      const float hn = acc[2][r] + bn;
      const float rg = 1.0f / (1.0f + __expf(-(xr[r] + hr)));
      const float zg = 1.0f / (1.0f + __expf(-(xz[r] + hz)));
      const float ng = tanhf(xnv[r] + rg * hn);
      const float hv2 = (1.0f - zg) * ng + zg * (hreg[r] * kb);
      hreg[r] = hv2;
      const unsigned mine = (unsigned)f2bf(hv2);
      const unsigned other = (unsigned)__shfl_xor((int)mine, 1, 64);
      if ((l15 & 1) == 0) {
        const unsigned packed = mine | (other << 16);
        __hip_atomic_store(&hout_u[((size_t)b * H_ + col) >> 1], packed,
                           __ATOMIC_RELAXED, __HIP_MEMORY_SCOPE_AGENT);
        __hip_atomic_store(
            &((unsigned*)hall)[(((size_t)b * Tc + tl) * H_ + col) >> 1],
            packed, __ATOMIC_RELAXED, __HIP_MEMORY_SCOPE_AGENT);
      }
    }

    // completion: drain own stores to LLC, join, bump the group counter
    __builtin_amdgcn_s_waitcnt(0);  // this wave's stores reached LLC
    __syncthreads();                // all 4 waves drained
    if (tid == 0) atomicAdd(cnt, 1);
  }

  // write back register h (write-through: later fences must not discard it)
  #pragma unroll
  for (int r = 0; r < 4; r++)
    __hip_atomic_store(&hf[(size_t)(b0 + r0 + r) * H_ + col], hreg[r],
                       __ATOMIC_RELAXED, __HIP_MEMORY_SCOPE_AGENT);
}

// ------------- heads: means & log_std fused (N=64), dual-dtype store ---------
__global__ __launch_bounds__(256) void heads_kernel(
    const unsigned short* __restrict__ feats,
    const unsigned short* __restrict__ Wm, const unsigned short* __restrict__ bm,
    const unsigned short* __restrict__ Wl, const unsigned short* __restrict__ bl,
    void* __restrict__ outbuf, int t0, int tcShift, const int* __restrict__ flag)
{
  __shared__ short Fs[64][40];
  __shared__ short Ws[64][40];
  const int fl = *flag;
  const int tid  = threadIdx.x;
  const int wave = tid >> 6, lane = tid & 63;
  const int quad = lane >> 4, l15 = lane & 15;
  const int m0 = blockIdx.x * 64;
  const int lrow = tid >> 2, lk = (tid & 3) * 8;
  f32x4 acc[4] = {};
  for (int k0 = 0; k0 < H_; k0 += 32) {
    __syncthreads();
    *(uint4*)&Fs[lrow][lk] = *(const uint4*)(feats + (size_t)(m0 + lrow) * H_ + k0 + lk);
    const unsigned short* wsrc = (lrow < 32)
        ? (Wm + (size_t)lrow * H_ + k0 + lk)
        : (Wl + (size_t)(lrow - 32) * H_ + k0 + lk);
    *(uint4*)&Ws[lrow][lk] = *(const uint4*)wsrc;
    __syncthreads();
    bf16x8 af = *(const bf16x8*)&Fs[wave * 16 + l15][quad * 8];
    #pragma unroll
    for (int j = 0; j < 4; j++) {
      bf16x8 bfv = *(const bf16x8*)&Ws[j * 16 + l15][quad * 8];
      acc[j] = __builtin_amdgcn_mfma_f32_16x16x32_bf16(af, bfv, acc[j], 0, 0, 0);
    }
  }
  const int tcMask = (1 << tcShift) - 1;
  const size_t lstdBase = (size_t)B_ * T_ * A_;
  #pragma unroll
  for (int j = 0; j < 4; j++) {
    const int col = j * 16 + l15;
    #pragma unroll
    for (int r = 0; r < 4; r++) {
      const int row = m0 + wave * 16 + quad * 4 + r;  // chunk-local
      const int grow = (row >> tcShift) * T_ + t0 + (row & tcMask);
      float v = acc[j][r];
      size_t idx;
      if (col < 32) {
        v += bf2f(bm[col]);
        idx = (size_t)grow * A_ + col;
      } else {
        v += bf2f(bl[col - 32]);
        v = fminf(fmaxf(v, -20.0f), 2.0f);
        idx = lstdBase + (size_t)grow * A_ + (col - 32);
      }
      if (fl) ((float*)outbuf)[idx] = v;
      else    ((unsigned short*)outbuf)[idx] = f2bf(v);
    }
  }
}

__global__ __launch_bounds__(256) void h0_cast(const void* __restrict__ h0,
                                               float* __restrict__ hf,
                                               unsigned short* __restrict__ hb0,
                                               const int* __restrict__ flag) {
  const int fl = *flag;
  int i = blockIdx.x * 256 + threadIdx.x;
  float v = fl ? ((const float*)h0)[i] : bf2f(((const unsigned short*)h0)[i]);
  hf[i] = v;
  hb0[i] = f2bf(v);
}
__global__ __launch_bounds__(256) void hfin_store(const float* __restrict__ h,
                                                  void* __restrict__ outbuf,
                                                  const int* __restrict__ flag) {
  const int fl = *flag;
  const size_t base = 2ull * B_ * T_ * A_;
  int i = blockIdx.x * 256 + threadIdx.x;
  if (fl) ((float*)outbuf)[base + i] = h[i];
  else    ((unsigned short*)outbuf)[base + i] = f2bf(h[i]);
}

extern "C" void kernel_launch(void* const* d_in, const int* in_sizes, int n_in,
                              void* d_out, int out_size, void* d_ws, size_t ws_size,
                              hipStream_t stream)
{
  const void* obs    = d_in[0];
  const void* h0in   = d_in[1];
  const int*  starts = (const int*)d_in[2];
  const void* fsrc[14] = { d_in[5], d_in[7], d_in[9], d_in[11], d_in[13], d_in[15],
                           d_in[3], d_in[4], d_in[6], d_in[8], d_in[10], d_in[12],
                           d_in[14], d_in[16] };
  const int fn[14] = { FC_ * D_, 3 * H_ * FC_, 3 * H_ * H_, H_ * H_, A_ * H_, A_ * H_,
                       D_, D_, FC_, 3 * H_, 3 * H_, H_, A_, A_ };

  char* ws = (char*)d_ws;
  int* flag = (int*)ws;
  size_t cur = 256;
  unsigned short* cdst[14];
  for (int i = 0; i < 14; i++) {
    cdst[i] = (unsigned short*)(ws + cur);
    cur += (size_t)fn[i] * 2;
    cur = (cur + 255) & ~255ull;
  }
  const size_t chunkBase = cur;
  const size_t fixedTail = 1048576ull /*hf*/ + 2ull * 524288ull /*hb0/1*/
                         + 32768ull /*flags*/;

  // Pick largest Tc with: chunkBase + Tc*2883584 + fixedTail <= ws_size
  int Tc = 1;
  for (int c = 32; c >= 1; c >>= 1) {
    size_t need = chunkBase + (size_t)c * 2883584ull + fixedTail;
    if (need <= ws_size) { Tc = c; break; }
  }
  int tcShift = 0;
  while ((1 << tcShift) < Tc) tcShift++;

  unsigned short* xn   = (unsigned short*)(ws + chunkBase);
  unsigned short* xfc  = (unsigned short*)(ws + chunkBase + (size_t)Tc * 262144ull);
  unsigned short* xg   = (unsigned short*)(ws + chunkBase + (size_t)Tc * 786432ull);
  unsigned short* hall = (unsigned short*)(ws + chunkBase + (size_t)Tc * 2359296ull);
  size_t o = chunkBase + (size_t)Tc * 2883584ull;
  float* hf           = (float*)(ws + o);           o += 1048576ull;
  unsigned short* hb0 = (unsigned short*)(ws + o);  o += 524288ull;
  unsigned short* hb1 = (unsigned short*)(ws + o);  o += 524288ull;
  int* flags          = (int*)(ws + o);             // bb counters, 128B apart
  unsigned short* feats = xg;  // xg dead once the chunk's scan is done

  const unsigned short *Wfc = cdst[0], *Wih = cdst[1], *Whh = cdst[2], *Wout = cdst[3];
  const unsigned short *Wmean = cdst[4], *Wls = cdst[5];
  const unsigned short *gam = cdst[6], *bet = cdst[7], *bfc = cdst[8], *bih = cdst[9];
  const unsigned short *bhh = cdst[10], *bout = cdst[11], *bmean = cdst[12], *bls = cdst[13];

  detect_kernel<<<dim3(1), dim3(256), 0, stream>>>((const unsigned short*)obs, flag);
  CanonArgs ca;
  int total = 0;
  for (int i = 0; i < 14; i++) {
    ca.src[i] = fsrc[i];
    ca.dst[i] = cdst[i];
    ca.ofs[i] = total;
    total += fn[i];
  }
  ca.ofs[14] = total;
  canon_kernel<<<dim3((total / 8 + 255) / 256), dim3(256), 0, stream>>>(ca, flag);
  h0_cast<<<dim3(B_ * H_ / 256), dim3(256), 0, stream>>>(h0in, hf, hb0, flag);
  hipMemsetAsync(flags, 0, 32768, stream);

  const int Mc = B_ * Tc;
  for (int t0 = 0; t0 < T_; t0 += Tc) {
    ln_kernel<<<dim3(Mc / 4), dim3(256), 0, stream>>>(obs, gam, bet, xn, t0, tcShift, flag);
    gemm_tn<<<dim3(FC_ / 128, Mc / 128), dim3(256), 0, stream>>>(
        xn, Wfc, bfc, xfc, Mc, FC_, D_, 1);
    gemm_tn<<<dim3(3 * H_ / 128, Mc / 128), dim3(256), 0, stream>>>(
        xfc, Wih, bih, xg, Mc, 3 * H_, FC_, 0);

    gru_scan<<<dim3(NWG_), dim3(256), 0, stream>>>(
        xg, starts, Whh, bhh, hf,
        (ull*)hb0, (ull*)hb1,
        hall, t0, Tc, flags);

    gemm_tn<<<dim3(H_ / 128, Mc / 128), dim3(256), 0, stream>>>(
        hall, Wout, bout, feats, Mc, H_, H_, 1);
    heads_kernel<<<dim3(Mc / 64), dim3(256), 0, stream>>>(
        feats, Wmean, bmean, Wls, bls, d_out, t0, tcShift, flag);
  }

  hfin_store<<<dim3(B_ * H_ / 256), dim3(256), 0, stream>>>(hf, d_out, flag);
}

// Round 5
// 2266.391 us; speedup vs baseline: 1.2087x; 1.2087x over previous
//
#include <hip/hip_runtime.h>
#include <hip/hip_bf16.h>

#define B_ 256
#define T_ 128
#define D_ 512
#define H_ 1024
#define FC_ 1024
#define A_ 32
#define NWG_ 256

typedef short bf16x8 __attribute__((ext_vector_type(8)));
typedef float f32x4 __attribute__((ext_vector_type(4)));
typedef unsigned long long ull;
typedef ull ullx2 __attribute__((ext_vector_type(2)));

__device__ __forceinline__ float bf2f(unsigned short u) {
  return __uint_as_float(((unsigned)u) << 16);
}
// round-to-nearest-even fp32 -> bf16
__device__ __forceinline__ unsigned short f2bf(float x) {
  unsigned u = __float_as_uint(x);
  u = u + 0x7fffu + ((u >> 16) & 1u);
  return (unsigned short)(u >> 16);
}
__device__ __forceinline__ void unpack8(uint4 v, float* f) {
  f[0] = bf2f(v.x & 0xffff); f[1] = bf2f(v.x >> 16);
  f[2] = bf2f(v.y & 0xffff); f[3] = bf2f(v.y >> 16);
  f[4] = bf2f(v.z & 0xffff); f[5] = bf2f(v.z >> 16);
  f[6] = bf2f(v.w & 0xffff); f[7] = bf2f(v.w >> 16);
}
__device__ __forceinline__ uint4 pack8(const float* f) {
  uint4 v;
  v.x = (unsigned)f2bf(f[0]) | ((unsigned)f2bf(f[1]) << 16);
  v.y = (unsigned)f2bf(f[2]) | ((unsigned)f2bf(f[3]) << 16);
  v.z = (unsigned)f2bf(f[4]) | ((unsigned)f2bf(f[5]) << 16);
  v.w = (unsigned)f2bf(f[6]) | ((unsigned)f2bf(f[7]) << 16);
  return v;
}

// ------------- dtype probe: bf16 inputs -> flag 0, fp32 inputs -> flag 1 -----
__global__ __launch_bounds__(256) void detect_kernel(
    const unsigned short* __restrict__ obs, int* __restrict__ flag)
{
  __shared__ int cnt;
  if (threadIdx.x == 0) cnt = 0;
  __syncthreads();
  int c = 0;
  for (int i = threadIdx.x; i < 8192; i += 256) {
    unsigned e = (obs[i] >> 7) & 0xffu;  // bf16 exponent field
    if (e >= 0x86u) c++;
  }
  atomicAdd(&cnt, c);
  __syncthreads();
  if (threadIdx.x == 0) *flag = (cnt >= 64) ? 1 : 0;
}

// ------------- canonicalize 14 float tensors to bf16 workspace copies -------
struct CanonArgs {
  const void* src[14];
  unsigned short* dst[14];
  int ofs[15];  // cumulative element offsets (all multiples of 8)
};
__global__ __launch_bounds__(256) void canon_kernel(CanonArgs a,
                                                    const int* __restrict__ flag)
{
  const int fl = *flag;
  const int i0 = (blockIdx.x * 256 + threadIdx.x) * 8;
  int t = 0;
  while (t < 14 && i0 >= a.ofs[t + 1]) t++;
  if (t >= 14) return;
  const int local = i0 - a.ofs[t];
  unsigned short* d = a.dst[t] + local;
  if (fl) {
    const float* s = (const float*)a.src[t] + local;
    #pragma unroll
    for (int e = 0; e < 8; e++) d[e] = f2bf(s[e]);
  } else {
    const unsigned short* s = (const unsigned short*)a.src[t] + local;
    #pragma unroll
    for (int e = 0; e < 8; e++) d[e] = s[e];
  }
}

// ---------------- LayerNorm: one wave per row of D=512 (chunked over t) ------
__global__ __launch_bounds__(256) void ln_kernel(
    const void* __restrict__ obs,
    const unsigned short* __restrict__ gamma_,
    const unsigned short* __restrict__ beta_,
    unsigned short* __restrict__ xn, int t0, int tcShift,
    const int* __restrict__ flag)
{
  const int fl = *flag;
  const int lane = threadIdx.x & 63;
  const int rloc = blockIdx.x * 4 + (threadIdx.x >> 6);
  const int b  = rloc >> tcShift;
  const int tl = rloc & ((1 << tcShift) - 1);
  const int grow = b * T_ + t0 + tl;
  float f[8];
  if (fl) {
    const float* of = (const float*)obs + (size_t)grow * D_ + lane * 8;
    const float4 v0 = *(const float4*)of;
    const float4 v1 = *(const float4*)(of + 4);
    f[0] = v0.x; f[1] = v0.y; f[2] = v0.z; f[3] = v0.w;
    f[4] = v1.x; f[5] = v1.y; f[6] = v1.z; f[7] = v1.w;
  } else {
    uint4 v = *(const uint4*)((const unsigned short*)obs + (size_t)grow * D_ + lane * 8);
    unpack8(v, f);
  }
  float s = 0.f, ss = 0.f;
  #pragma unroll
  for (int i = 0; i < 8; i++) { s += f[i]; ss += f[i] * f[i]; }
  #pragma unroll
  for (int off = 32; off > 0; off >>= 1) {
    s  += __shfl_xor(s,  off, 64);
    ss += __shfl_xor(ss, off, 64);
  }
  const float mu  = s * (1.0f / D_);
  const float var = ss * (1.0f / D_) - mu * mu;
  const float inv = rsqrtf(var + 1e-5f);
  float g[8], b8[8];
  unpack8(*(const uint4*)(gamma_ + lane * 8), g);
  unpack8(*(const uint4*)(beta_  + lane * 8), b8);
  float o[8];
  #pragma unroll
  for (int i = 0; i < 8; i++) o[i] = (f[i] - mu) * inv * g[i] + b8[i];
  *(uint4*)(xn + (size_t)rloc * D_ + lane * 8) = pack8(o);
}

// ------------- generic TN GEMM: C[M,N] = A[M,K] * B[N,K]^T + bias -------------
// m97 structure: 128x128 tile, BK=32, linear LDS, global_load_lds width=16,
// 2-barrier K-loop. Staging never touches VGPRs.
__global__ __launch_bounds__(256) void gemm_tn(
    const unsigned short* __restrict__ A, const unsigned short* __restrict__ Bm,
    const unsigned short* __restrict__ bias, unsigned short* __restrict__ C,
    int M, int N, int K, int relu)
{
  __shared__ short As[128 * 32];   // [row][k] linear, 8KB
  __shared__ short Bs[128 * 32];
  const int tid  = threadIdx.x;
  const int wave = tid >> 6, lane = tid & 63;
  const int quad = lane >> 4, l15 = lane & 15;
  const int m0 = blockIdx.y * 128, n0 = blockIdx.x * 128;
  const int wm = (wave >> 1) * 64, wn = (wave & 1) * 64;
  const int srow = tid >> 2;          // 0..63
  const int skc  = (tid & 3) * 8;     // shorts
  const size_t aoff0 = (size_t)(m0 + srow) * K + skc;
  const size_t aoff1 = (size_t)(m0 + 64 + srow) * K + skc;
  const size_t boff0 = (size_t)(n0 + srow) * K + skc;
  const size_t boff1 = (size_t)(n0 + 64 + srow) * K + skc;
  const int lb0 = wave * 512;          // shorts
  const int lb1 = 2048 + wave * 512;
  f32x4 acc[4][4] = {};
  for (int k0 = 0; k0 < K; k0 += 32) {
    __syncthreads();
    __builtin_amdgcn_global_load_lds(
        (const __attribute__((address_space(1))) unsigned*)(A + aoff0 + k0),
        (__attribute__((address_space(3))) unsigned*)&As[lb0], 16, 0, 0);
    __builtin_amdgcn_global_load_lds(
        (const __attribute__((address_space(1))) unsigned*)(A + aoff1 + k0),
        (__attribute__((address_space(3))) unsigned*)&As[lb1], 16, 0, 0);
    __builtin_amdgcn_global_load_lds(
        (const __attribute__((address_space(1))) unsigned*)(Bm + boff0 + k0),
        (__attribute__((address_space(3))) unsigned*)&Bs[lb0], 16, 0, 0);
    __builtin_amdgcn_global_load_lds(
        (const __attribute__((address_space(1))) unsigned*)(Bm + boff1 + k0),
        (__attribute__((address_space(3))) unsigned*)&Bs[lb1], 16, 0, 0);
    __syncthreads();  // compiler drains vmcnt before barrier
    bf16x8 af[4], bfv[4];
    #pragma unroll
    for (int i = 0; i < 4; i++) af[i]  = *(const bf16x8*)&As[(wm + i * 16 + l15) * 32 + quad * 8];
    #pragma unroll
    for (int j = 0; j < 4; j++) bfv[j] = *(const bf16x8*)&Bs[(wn + j * 16 + l15) * 32 + quad * 8];
    #pragma unroll
    for (int i = 0; i < 4; i++)
      #pragma unroll
      for (int j = 0; j < 4; j++)
        acc[i][j] = __builtin_amdgcn_mfma_f32_16x16x32_bf16(af[i], bfv[j], acc[i][j], 0, 0, 0);
  }
  #pragma unroll
  for (int j = 0; j < 4; j++) {
    const int col = n0 + wn + j * 16 + l15;
    const float bj = bias ? bf2f(bias[col]) : 0.0f;
    #pragma unroll
    for (int i = 0; i < 4; i++) {
      const int row = m0 + wm + i * 16 + quad * 4;
      #pragma unroll
      for (int r = 0; r < 4; r++) {
        float v = acc[i][j][r] + bj;
        if (relu) v = fmaxf(v, 0.0f);
        C[(size_t)(row + r) * N + col] = f2bf(v);
      }
    }
  }
}

// ---------------- persistent GRU scan (fence-free LLC protocol) --------------
// 256 WGs (1/CU). WG = (bb,jb): bb owns 64 batches, jb owns 16 cols x 3 gates.
// W_hh slice (96KB) + starts bitmask in LDS once. h fp32 in registers.
// v6 = v5 with the staging addressing corrected (v5's failure):
//   h row = H_=1024 bf16 = 256 ull (was 128); chunk = 128 bf16 = 32 ull (was 16).
// Design (unchanged from v5): wave-private staging, ZERO intra-step barriers.
//  * Forcing chain global_load -> reg -> ds_write -> ds_read -> MFMA survives
//    hipcc scheduling (v1); register-only paths (v2/v4) get re-serialized.
//  * Each wave stages only ITS 16 rows into a wave-private Hs slab; v1's two
//    per-chunk __syncthreads (16/step) are gone.
//  * Writer<->reader lane maps are CROSS-LANE (writer lane l covers row l>>2,
//    shorts (l&3)*32..+32 of the chunk window; reader lane reads row l15,
//    shorts w4*32+quad*8) so store-forward elision (v3) is impossible.
//  * 4-chunk-deep register prefetch; sched_barrier(0) between chunk regions
//    replaces v1's barriers as the placement pin.
__global__ __launch_bounds__(256, 1) void gru_scan(
    const unsigned short* __restrict__ xg,   // chunk-local [B][Tc][3H]
    const int* __restrict__ starts,
    const unsigned short* __restrict__ Whh,
    const unsigned short* __restrict__ bhh,
    float* __restrict__ hf,                  // [B][H] fp32 master
    ull* __restrict__ hb0,                   // bf16 mirror ping (8B units)
    ull* __restrict__ hb1,                   // bf16 mirror pong
    unsigned short* __restrict__ hall,       // [B][Tc][H] bf16
    int t0, int Tc,
    int* __restrict__ flags)                 // [NWG_] step flags, 128B stride
{
  __shared__ short Ws[3 * 16 * 1032];   // 99 KB: [g][jj][k] stride 1032
  __shared__ short Hs[4 * 2 * 2176];    // 34 KB: per-wave dbuf, 16 rows x 136
  __shared__ unsigned sbits[64][4];     // starts bitmask: 64 rows x 128 bits
  const int tid  = threadIdx.x;
  const int wg   = blockIdx.x;
  const int jb   = wg & 63, bb = wg >> 6;
  const int j0   = jb * 16, b0 = bb * 64;
  const int wave = tid >> 6, lane = tid & 63;
  const int quad = lane >> 4, l15 = lane & 15;

  // one-time: W_hh slice -> LDS (48 rows x 1024 k)
  for (int c = tid; c < 48 * 128; c += 256) {
    const int row = c >> 7;          // g*16 + jj
    const int kc  = (c & 127) * 8;
    const int g = row >> 4, jj = row & 15;
    *(uint4*)&Ws[row * 1032 + kc] =
        *(const uint4*)(Whh + (size_t)(g * H_ + j0 + jj) * H_ + kc);
  }
  // one-time: starts -> bitmask
  for (int c = tid; c < 64 * 4; c += 256) {
    const int row = c >> 2, w = c & 3;
    unsigned m = 0;
    #pragma unroll
    for (int bi = 0; bi < 32; bi++)
      m |= (starts[(b0 + row) * T_ + w * 32 + bi] ? 1u : 0u) << bi;
    sbits[row][w] = m;
  }
  const float br = bf2f(bhh[j0 + l15]);
  const float bz = bf2f(bhh[H_ + j0 + l15]);
  const float bn = bf2f(bhh[2 * H_ + j0 + l15]);
  const int col = j0 + l15;

  // register-resident fp32 h: 4 owned slots (rows r0..r0+3, col)
  const int r0 = wave * 16 + quad * 4;
  float hreg[4];
  #pragma unroll
  for (int r = 0; r < 4; r++)
    hreg[r] = hf[(size_t)(b0 + r0 + r) * H_ + col];

  // staging maps (all within this wave's 16 rows)
  const int wrow = lane >> 2;                 // writer: row 0..15
  const int wseg = (lane & 3) * 32;           // writer: col segment (shorts)
  // h row = 1024 bf16 = 256 ull; lane's segment = 32 shorts = 8 ull
  const size_t hoff = (size_t)(b0 + wave * 16 + wrow) * 256 + (lane & 3) * 8;
  const int hsWr = wave * 4352 + wrow * 136 + wseg;   // shorts
  const int hsRd = wave * 4352 + l15 * 136 + quad * 8;
  const short* wsb = &Ws[l15 * 1032 + quad * 8];

  __syncthreads();  // Ws / sbits ready

// issue the 8 LLC loads (8B each) for chunk c into dst[8]
// chunk = 128 bf16 cols = 32 ull
#define GRU_LOADC(dst, c)                                                     \
  { _Pragma("unroll")                                                         \
    for (int i = 0; i < 8; i++)                                               \
      dst[i] = __hip_atomic_load(hrow + (c) * 32 + i, __ATOMIC_RELAXED,       \
                                 __HIP_MEMORY_SCOPE_AGENT); }

// masked ds_write of chunk c (4x b128), then 12 MFMAs consuming it
#define GRU_SM(src, c)                                                        \
  { _Pragma("unroll")                                                         \
    for (int u = 0; u < 4; u++) {                                             \
      ullx2 u2;                                                               \
      u2.x = src[2 * u] & keepW;                                              \
      u2.y = src[2 * u + 1] & keepW;                                          \
      *(uint4*)&Hs[hsWr + ((c) & 1) * 2176 + u * 8] =                         \
          __builtin_bit_cast(uint4, u2);                                      \
    }                                                                         \
    _Pragma("unroll")                                                         \
    for (int w4 = 0; w4 < 4; w4++) {                                          \
      const bf16x8 a =                                                        \
          *(const bf16x8*)&Hs[hsRd + ((c) & 1) * 2176 + w4 * 32];             \
      acc[0] = __builtin_amdgcn_mfma_f32_16x16x32_bf16(                       \
          a, *(const bf16x8*)(wsb + 0 * 16512 + ((c) * 4 + w4) * 32),         \
          acc[0], 0, 0, 0);                                                   \
      acc[1] = __builtin_amdgcn_mfma_f32_16x16x32_bf16(                       \
          a, *(const bf16x8*)(wsb + 1 * 16512 + ((c) * 4 + w4) * 32),         \
          acc[1], 0, 0, 0);                                                   \
      acc[2] = __builtin_amdgcn_mfma_f32_16x16x32_bf16(                       \
          a, *(const bf16x8*)(wsb + 2 * 16512 + ((c) * 4 + w4) * 32),         \
          acc[2], 0, 0, 0);                                                   \
    } }

#define GRU_SB __builtin_amdgcn_sched_barrier(0);

  for (int tl = 0; tl < Tc; tl++) {
    const int t = t0 + tl;
    const ull* hin = (t & 1) ? hb1 : hb0;
    unsigned* hout_u = (unsigned*)((t & 1) ? hb0 : hb1);
    const unsigned tw = (unsigned)(t >> 5), tb = (unsigned)(t & 31);
    const ull* hrow = hin + hoff;

    // 4-chunk-deep LLC prefetch into registers
    ull pf0[8], pf1[8], pf2[8], pf3[8];
    GRU_LOADC(pf0, 0)
    GRU_LOADC(pf1, 1)
    GRU_LOADC(pf2, 2)
    GRU_LOADC(pf3, 3)

    // this step's xg values (12 scalar loads, consumed in epilogue)
    float xr[4], xz[4], xnv[4];
    #pragma unroll
    for (int r = 0; r < 4; r++) {
      const size_t xrow = ((size_t)(b0 + r0 + r) * Tc + tl) * (3 * H_);
      xr[r]  = bf2f(xg[xrow + col]);
      xz[r]  = bf2f(xg[xrow + H_ + col]);
      xnv[r] = bf2f(xg[xrow + 2 * H_ + col]);
    }

    // episode-start mask for this lane's WRITER row
    const ull keepW = ((sbits[wave * 16 + wrow][tw] >> tb) & 1u) ? 0ull : ~0ull;

    f32x4 acc[3] = {};
    GRU_SB
    GRU_SM(pf0, 0) GRU_LOADC(pf0, 4) GRU_SB
    GRU_SM(pf1, 1) GRU_LOADC(pf1, 5) GRU_SB
    GRU_SM(pf2, 2) GRU_LOADC(pf2, 6) GRU_SB
    GRU_SM(pf3, 3) GRU_LOADC(pf3, 7) GRU_SB
    GRU_SM(pf0, 4) GRU_SB
    GRU_SM(pf1, 5) GRU_SB
    GRU_SM(pf2, 6) GRU_SB
    GRU_SM(pf3, 7)

    // epilogue: gate math in registers; pack col pairs; atomic store to LLC
    #pragma unroll
    for (int r = 0; r < 4; r++) {
      const int lrow = r0 + r;
      const int b = b0 + lrow;
      const float kb = ((sbits[lrow][tw] >> tb) & 1u) ? 0.0f : 1.0f;
      const float hr = acc[0][r] + br;
      const float hz = acc[1][r] + bz;
      const float hn = acc[2][r] + bn;
      const float rg = 1.0f / (1.0f + __expf(-(xr[r] + hr)));
      const float zg = 1.0f / (1.0f + __expf(-(xz[r] + hz)));
      const float ng = tanhf(xnv[r] + rg * hn);
      const float hv = (1.0f - zg) * ng + zg * (hreg[r] * kb);
      hreg[r] = hv;
      const unsigned mine = (unsigned)f2bf(hv);
      const unsigned other = (unsigned)__shfl_xor((int)mine, 1, 64);
      if ((l15 & 1) == 0) {
        const unsigned packed = mine | (other << 16);
        __hip_atomic_store(&hout_u[((size_t)b * H_ + col) >> 1], packed,
                           __ATOMIC_RELAXED, __HIP_MEMORY_SCOPE_AGENT);
        ((unsigned*)hall)[(((size_t)b * Tc + tl) * H_ + col) >> 1] = packed;
      }
    }

    // fence-free barrier: drain own stores, join, store flag, poll group
    const int my = t0 + tl + 1;
    __builtin_amdgcn_s_waitcnt(0);  // this wave's atomic stores reached LLC
    __syncthreads();                // all 4 waves drained
    if (tid == 0)
      __hip_atomic_store(&flags[wg * 32], my, __ATOMIC_RELAXED,
                         __HIP_MEMORY_SCOPE_AGENT);
    if (tid < 64) {
      while (__hip_atomic_load(&flags[(bb * 64 + tid) * 32], __ATOMIC_RELAXED,
                               __HIP_MEMORY_SCOPE_AGENT) < my)
        __builtin_amdgcn_s_sleep(1);
    }
    __syncthreads();
  }
#undef GRU_LOADC
#undef GRU_SM
#undef GRU_SB

  // write back register h to fp32 master (read by next dispatch / hfin_store)
  #pragma unroll
  for (int r = 0; r < 4; r++)
    hf[(size_t)(b0 + r0 + r) * H_ + col] = hreg[r];
}

// ------------- heads: means & log_std fused (N=64), dual-dtype store ---------
__global__ __launch_bounds__(256) void heads_kernel(
    const unsigned short* __restrict__ feats,
    const unsigned short* __restrict__ Wm, const unsigned short* __restrict__ bm,
    const unsigned short* __restrict__ Wl, const unsigned short* __restrict__ bl,
    void* __restrict__ outbuf, int t0, int tcShift, const int* __restrict__ flag)
{
  __shared__ short Fs[64][40];
  __shared__ short Ws[64][40];
  const int fl = *flag;
  const int tid  = threadIdx.x;
  const int wave = tid >> 6, lane = tid & 63;
  const int quad = lane >> 4, l15 = lane & 15;
  const int m0 = blockIdx.x * 64;
  const int lrow = tid >> 2, lk = (tid & 3) * 8;
  f32x4 acc[4] = {};
  for (int k0 = 0; k0 < H_; k0 += 32) {
    __syncthreads();
    *(uint4*)&Fs[lrow][lk] = *(const uint4*)(feats + (size_t)(m0 + lrow) * H_ + k0 + lk);
    const unsigned short* wsrc = (lrow < 32)
        ? (Wm + (size_t)lrow * H_ + k0 + lk)
        : (Wl + (size_t)(lrow - 32) * H_ + k0 + lk);
    *(uint4*)&Ws[lrow][lk] = *(const uint4*)wsrc;
    __syncthreads();
    bf16x8 af = *(const bf16x8*)&Fs[wave * 16 + l15][quad * 8];
    #pragma unroll
    for (int j = 0; j < 4; j++) {
      bf16x8 bfv = *(const bf16x8*)&Ws[j * 16 + l15][quad * 8];
      acc[j] = __builtin_amdgcn_mfma_f32_16x16x32_bf16(af, bfv, acc[j], 0, 0, 0);
    }
  }
  const int tcMask = (1 << tcShift) - 1;
  const size_t lstdBase = (size_t)B_ * T_ * A_;
  #pragma unroll
  for (int j = 0; j < 4; j++) {
    const int col = j * 16 + l15;
    #pragma unroll
    for (int r = 0; r < 4; r++) {
      const int row = m0 + wave * 16 + quad * 4 + r;  // chunk-local
      const int grow = (row >> tcShift) * T_ + t0 + (row & tcMask);
      float v = acc[j][r];
      size_t idx;
      if (col < 32) {
        v += bf2f(bm[col]);
        idx = (size_t)grow * A_ + col;
      } else {
        v += bf2f(bl[col - 32]);
        v = fminf(fmaxf(v, -20.0f), 2.0f);
        idx = lstdBase + (size_t)grow * A_ + (col - 32);
      }
      if (fl) ((float*)outbuf)[idx] = v;
      else    ((unsigned short*)outbuf)[idx] = f2bf(v);
    }
  }
}

__global__ __launch_bounds__(256) void h0_cast(const void* __restrict__ h0,
                                               float* __restrict__ hf,
                                               unsigned short* __restrict__ hb0,
                                               const int* __restrict__ flag) {
  const int fl = *flag;
  int i = blockIdx.x * 256 + threadIdx.x;
  float v = fl ? ((const float*)h0)[i] : bf2f(((const unsigned short*)h0)[i]);
  hf[i] = v;
  hb0[i] = f2bf(v);
}
__global__ __launch_bounds__(256) void hfin_store(const float* __restrict__ h,
                                                  void* __restrict__ outbuf,
                                                  const int* __restrict__ flag) {
  const int fl = *flag;
  const size_t base = 2ull * B_ * T_ * A_;
  int i = blockIdx.x * 256 + threadIdx.x;
  if (fl) ((float*)outbuf)[base + i] = h[i];
  else    ((unsigned short*)outbuf)[base + i] = f2bf(h[i]);
}

extern "C" void kernel_launch(void* const* d_in, const int* in_sizes, int n_in,
                              void* d_out, int out_size, void* d_ws, size_t ws_size,
                              hipStream_t stream)
{
  const void* obs    = d_in[0];
  const void* h0in   = d_in[1];
  const int*  starts = (const int*)d_in[2];
  const void* fsrc[14] = { d_in[5], d_in[7], d_in[9], d_in[11], d_in[13], d_in[15],
                           d_in[3], d_in[4], d_in[6], d_in[8], d_in[10], d_in[12],
                           d_in[14], d_in[16] };
  const int fn[14] = { FC_ * D_, 3 * H_ * FC_, 3 * H_ * H_, H_ * H_, A_ * H_, A_ * H_,
                       D_, D_, FC_, 3 * H_, 3 * H_, H_, A_, A_ };

  char* ws = (char*)d_ws;
  int* flag = (int*)ws;
  size_t cur = 256;
  unsigned short* cdst[14];
  for (int i = 0; i < 14; i++) {
    cdst[i] = (unsigned short*)(ws + cur);
    cur += (size_t)fn[i] * 2;
    cur = (cur + 255) & ~255ull;
  }
  const size_t chunkBase = cur;
  const size_t fixedTail = 1048576ull /*hf*/ + 2ull * 524288ull /*hb0/1*/
                         + 32768ull /*flags*/;

  // Pick largest Tc with: chunkBase + Tc*2883584 + fixedTail <= ws_size
  int Tc = 1;
  for (int c = 32; c >= 1; c >>= 1) {
    size_t need = chunkBase + (size_t)c * 2883584ull + fixedTail;
    if (need <= ws_size) { Tc = c; break; }
  }
  int tcShift = 0;
  while ((1 << tcShift) < Tc) tcShift++;

  unsigned short* xn   = (unsigned short*)(ws + chunkBase);
  unsigned short* xfc  = (unsigned short*)(ws + chunkBase + (size_t)Tc * 262144ull);
  unsigned short* xg   = (unsigned short*)(ws + chunkBase + (size_t)Tc * 786432ull);
  unsigned short* hall = (unsigned short*)(ws + chunkBase + (size_t)Tc * 2359296ull);
  size_t o = chunkBase + (size_t)Tc * 2883584ull;
  float* hf           = (float*)(ws + o);           o += 1048576ull;
  unsigned short* hb0 = (unsigned short*)(ws + o);  o += 524288ull;
  unsigned short* hb1 = (unsigned short*)(ws + o);  o += 524288ull;
  int* flags          = (int*)(ws + o);             // NWG_ x 128B
  unsigned short* feats = xg;  // xg dead once the chunk's scan is done

  const unsigned short *Wfc = cdst[0], *Wih = cdst[1], *Whh = cdst[2], *Wout = cdst[3];
  const unsigned short *Wmean = cdst[4], *Wls = cdst[5];
  const unsigned short *gam = cdst[6], *bet = cdst[7], *bfc = cdst[8], *bih = cdst[9];
  const unsigned short *bhh = cdst[10], *bout = cdst[11], *bmean = cdst[12], *bls = cdst[13];

  detect_kernel<<<dim3(1), dim3(256), 0, stream>>>((const unsigned short*)obs, flag);
  CanonArgs ca;
  int total = 0;
  for (int i = 0; i < 14; i++) {
    ca.src[i] = fsrc[i];
    ca.dst[i] = cdst[i];
    ca.ofs[i] = total;
    total += fn[i];
  }
  ca.ofs[14] = total;
  canon_kernel<<<dim3((total / 8 + 255) / 256), dim3(256), 0, stream>>>(ca, flag);
  h0_cast<<<dim3(B_ * H_ / 256), dim3(256), 0, stream>>>(h0in, hf, hb0, flag);
  hipMemsetAsync(flags, 0, 32768, stream);

  const int Mc = B_ * Tc;
  for (int t0 = 0; t0 < T_; t0 += Tc) {
    ln_kernel<<<dim3(Mc / 4), dim3(256), 0, stream>>>(obs, gam, bet, xn, t0, tcShift, flag);
    gemm_tn<<<dim3(FC_ / 128, Mc / 128), dim3(256), 0, stream>>>(
        xn, Wfc, bfc, xfc, Mc, FC_, D_, 1);
    gemm_tn<<<dim3(3 * H_ / 128, Mc / 128), dim3(256), 0, stream>>>(
        xfc, Wih, bih, xg, Mc, 3 * H_, FC_, 0);

    gru_scan<<<dim3(NWG_), dim3(256), 0, stream>>>(
        xg, starts, Whh, bhh, hf,
        (ull*)hb0, (ull*)hb1,
        hall, t0, Tc, flags);

    gemm_tn<<<dim3(H_ / 128, Mc / 128), dim3(256), 0, stream>>>(
        hall, Wout, bout, feats, Mc, H_, H_, 1);
    heads_kernel<<<dim3(Mc / 64), dim3(256), 0, stream>>>(
        feats, Wmean, bmean, Wls, bls, d_out, t0, tcShift, flag);
  }

  hfin_store<<<dim3(B_ * H_ / 256), dim3(256), 0, stream>>>(hf, d_out, flag);
}

// Round 6
// 1784.462 us; speedup vs baseline: 1.5352x; 1.2701x over previous
//
#include <hip/hip_runtime.h>
#include <hip/hip_bf16.h>

#define B_ 256
#define T_ 128
#define D_ 512
#define H_ 1024
#define FC_ 1024
#define A_ 32
#define NWG_ 256

typedef short bf16x8 __attribute__((ext_vector_type(8)));
typedef float f32x4 __attribute__((ext_vector_type(4)));
typedef unsigned long long ull;

__device__ __forceinline__ float bf2f(unsigned short u) {
  return __uint_as_float(((unsigned)u) << 16);
}
// round-to-nearest-even fp32 -> bf16
__device__ __forceinline__ unsigned short f2bf(float x) {
  unsigned u = __float_as_uint(x);
  u = u + 0x7fffu + ((u >> 16) & 1u);
  return (unsigned short)(u >> 16);
}
__device__ __forceinline__ void unpack8(uint4 v, float* f) {
  f[0] = bf2f(v.x & 0xffff); f[1] = bf2f(v.x >> 16);
  f[2] = bf2f(v.y & 0xffff); f[3] = bf2f(v.y >> 16);
  f[4] = bf2f(v.z & 0xffff); f[5] = bf2f(v.z >> 16);
  f[6] = bf2f(v.w & 0xffff); f[7] = bf2f(v.w >> 16);
}
__device__ __forceinline__ uint4 pack8(const float* f) {
  uint4 v;
  v.x = (unsigned)f2bf(f[0]) | ((unsigned)f2bf(f[1]) << 16);
  v.y = (unsigned)f2bf(f[2]) | ((unsigned)f2bf(f[3]) << 16);
  v.z = (unsigned)f2bf(f[4]) | ((unsigned)f2bf(f[5]) << 16);
  v.w = (unsigned)f2bf(f[6]) | ((unsigned)f2bf(f[7]) << 16);
  return v;
}

// ------------- dtype probe: bf16 inputs -> flag 0, fp32 inputs -> flag 1 -----
__global__ __launch_bounds__(256) void detect_kernel(
    const unsigned short* __restrict__ obs, int* __restrict__ flag)
{
  __shared__ int cnt;
  if (threadIdx.x == 0) cnt = 0;
  __syncthreads();
  int c = 0;
  for (int i = threadIdx.x; i < 8192; i += 256) {
    unsigned e = (obs[i] >> 7) & 0xffu;  // bf16 exponent field
    if (e >= 0x86u) c++;
  }
  atomicAdd(&cnt, c);
  __syncthreads();
  if (threadIdx.x == 0) *flag = (cnt >= 64) ? 1 : 0;
}

// ------------- canonicalize 14 float tensors to bf16 workspace copies -------
struct CanonArgs {
  const void* src[14];
  unsigned short* dst[14];
  int ofs[15];  // cumulative element offsets (all multiples of 8)
};
__global__ __launch_bounds__(256) void canon_kernel(CanonArgs a,
                                                    const int* __restrict__ flag)
{
  const int fl = *flag;
  const int i0 = (blockIdx.x * 256 + threadIdx.x) * 8;
  int t = 0;
  while (t < 14 && i0 >= a.ofs[t + 1]) t++;
  if (t >= 14) return;
  const int local = i0 - a.ofs[t];
  unsigned short* d = a.dst[t] + local;
  if (fl) {
    const float* s = (const float*)a.src[t] + local;
    #pragma unroll
    for (int e = 0; e < 8; e++) d[e] = f2bf(s[e]);
  } else {
    const unsigned short* s = (const unsigned short*)a.src[t] + local;
    #pragma unroll
    for (int e = 0; e < 8; e++) d[e] = s[e];
  }
}

// ---------------- LayerNorm: one wave per row of D=512 (chunked over t) ------
__global__ __launch_bounds__(256) void ln_kernel(
    const void* __restrict__ obs,
    const unsigned short* __restrict__ gamma_,
    const unsigned short* __restrict__ beta_,
    unsigned short* __restrict__ xn, int t0, int tcShift,
    const int* __restrict__ flag)
{
  const int fl = *flag;
  const int lane = threadIdx.x & 63;
  const int rloc = blockIdx.x * 4 + (threadIdx.x >> 6);
  const int b  = rloc >> tcShift;
  const int tl = rloc & ((1 << tcShift) - 1);
  const int grow = b * T_ + t0 + tl;
  float f[8];
  if (fl) {
    const float* of = (const float*)obs + (size_t)grow * D_ + lane * 8;
    const float4 v0 = *(const float4*)of;
    const float4 v1 = *(const float4*)(of + 4);
    f[0] = v0.x; f[1] = v0.y; f[2] = v0.z; f[3] = v0.w;
    f[4] = v1.x; f[5] = v1.y; f[6] = v1.z; f[7] = v1.w;
  } else {
    uint4 v = *(const uint4*)((const unsigned short*)obs + (size_t)grow * D_ + lane * 8);
    unpack8(v, f);
  }
  float s = 0.f, ss = 0.f;
  #pragma unroll
  for (int i = 0; i < 8; i++) { s += f[i]; ss += f[i] * f[i]; }
  #pragma unroll
  for (int off = 32; off > 0; off >>= 1) {
    s  += __shfl_xor(s,  off, 64);
    ss += __shfl_xor(ss, off, 64);
  }
  const float mu  = s * (1.0f / D_);
  const float var = ss * (1.0f / D_) - mu * mu;
  const float inv = rsqrtf(var + 1e-5f);
  float g[8], b8[8];
  unpack8(*(const uint4*)(gamma_ + lane * 8), g);
  unpack8(*(const uint4*)(beta_  + lane * 8), b8);
  float o[8];
  #pragma unroll
  for (int i = 0; i < 8; i++) o[i] = (f[i] - mu) * inv * g[i] + b8[i];
  *(uint4*)(xn + (size_t)rloc * D_ + lane * 8) = pack8(o);
}

// ------------- generic TN GEMM: C[M,N] = A[M,K] * B[N,K]^T + bias -------------
// m97 structure: 128x128 tile, BK=32, linear LDS, global_load_lds width=16,
// 2-barrier K-loop. Staging never touches VGPRs.
__global__ __launch_bounds__(256) void gemm_tn(
    const unsigned short* __restrict__ A, const unsigned short* __restrict__ Bm,
    const unsigned short* __restrict__ bias, unsigned short* __restrict__ C,
    int M, int N, int K, int relu)
{
  __shared__ short As[128 * 32];   // [row][k] linear, 8KB
  __shared__ short Bs[128 * 32];
  const int tid  = threadIdx.x;
  const int wave = tid >> 6, lane = tid & 63;
  const int quad = lane >> 4, l15 = lane & 15;
  const int m0 = blockIdx.y * 128, n0 = blockIdx.x * 128;
  const int wm = (wave >> 1) * 64, wn = (wave & 1) * 64;
  const int srow = tid >> 2;          // 0..63
  const int skc  = (tid & 3) * 8;     // shorts
  const size_t aoff0 = (size_t)(m0 + srow) * K + skc;
  const size_t aoff1 = (size_t)(m0 + 64 + srow) * K + skc;
  const size_t boff0 = (size_t)(n0 + srow) * K + skc;
  const size_t boff1 = (size_t)(n0 + 64 + srow) * K + skc;
  const int lb0 = wave * 512;          // shorts
  const int lb1 = 2048 + wave * 512;
  f32x4 acc[4][4] = {};
  for (int k0 = 0; k0 < K; k0 += 32) {
    __syncthreads();
    __builtin_amdgcn_global_load_lds(
        (const __attribute__((address_space(1))) unsigned*)(A + aoff0 + k0),
        (__attribute__((address_space(3))) unsigned*)&As[lb0], 16, 0, 0);
    __builtin_amdgcn_global_load_lds(
        (const __attribute__((address_space(1))) unsigned*)(A + aoff1 + k0),
        (__attribute__((address_space(3))) unsigned*)&As[lb1], 16, 0, 0);
    __builtin_amdgcn_global_load_lds(
        (const __attribute__((address_space(1))) unsigned*)(Bm + boff0 + k0),
        (__attribute__((address_space(3))) unsigned*)&Bs[lb0], 16, 0, 0);
    __builtin_amdgcn_global_load_lds(
        (const __attribute__((address_space(1))) unsigned*)(Bm + boff1 + k0),
        (__attribute__((address_space(3))) unsigned*)&Bs[lb1], 16, 0, 0);
    __syncthreads();  // compiler drains vmcnt before barrier
    bf16x8 af[4], bfv[4];
    #pragma unroll
    for (int i = 0; i < 4; i++) af[i]  = *(const bf16x8*)&As[(wm + i * 16 + l15) * 32 + quad * 8];
    #pragma unroll
    for (int j = 0; j < 4; j++) bfv[j] = *(const bf16x8*)&Bs[(wn + j * 16 + l15) * 32 + quad * 8];
    #pragma unroll
    for (int i = 0; i < 4; i++)
      #pragma unroll
      for (int j = 0; j < 4; j++)
        acc[i][j] = __builtin_amdgcn_mfma_f32_16x16x32_bf16(af[i], bfv[j], acc[i][j], 0, 0, 0);
  }
  #pragma unroll
  for (int j = 0; j < 4; j++) {
    const int col = n0 + wn + j * 16 + l15;
    const float bj = bias ? bf2f(bias[col]) : 0.0f;
    #pragma unroll
    for (int i = 0; i < 4; i++) {
      const int row = m0 + wm + i * 16 + quad * 4;
      #pragma unroll
      for (int r = 0; r < 4; r++) {
        float v = acc[i][j][r] + bj;
        if (relu) v = fmaxf(v, 0.0f);
        C[(size_t)(row + r) * N + col] = f2bf(v);
      }
    }
  }
}

// ---------------- persistent GRU scan (fence-free LLC protocol) --------------
// 256 WGs (1/CU). WG = (bb,jb): bb owns 64 batches, jb owns 16 cols x 3 gates.
// W_hh slice (96KB) + starts bitmask in LDS once. h fp32 in registers.
// v7 = v1's PROVEN structure (cross-wave cooperative staging, barrier-pinned
// prefetch->ds_write->ds_read->MFMA chain) with two parameter changes:
//  * 2 chunks per barrier pair (4 pairs/step): barriers 16 -> 8 per step.
//    Hs = 2 slots of [64][136] (34.8 KB total; LDS 134912 B, fits).
//  * Prefetch 2 chunks ahead (pf0+pf1): loads for chunks 2p+2/2p+3 issue after
//    pair p's write-barrier, consumed after pair p+1's barrier (~2x latency
//    cover of v1).
// Evidence basis: v2/v3/v4 (register-only) re-serialize at the compiler's
// ~132-reg target; v6 (wave-private LDS, 0 barriers) materialized but lost to
// v1 (405 vs 296) -> barriers are not the dominant cost; v1's staging map is.
__global__ __launch_bounds__(256, 1) void gru_scan(
    const unsigned short* __restrict__ xg,   // chunk-local [B][Tc][3H]
    const int* __restrict__ starts,
    const unsigned short* __restrict__ Whh,
    const unsigned short* __restrict__ bhh,
    float* __restrict__ hf,                  // [B][H] fp32 master
    ull* __restrict__ hb0,                   // bf16 mirror ping (8B units)
    ull* __restrict__ hb1,                   // bf16 mirror pong
    unsigned short* __restrict__ hall,       // [B][Tc][H] bf16
    int t0, int Tc,
    int* __restrict__ flags)                 // [NWG_] step flags, 128B stride
{
  __shared__ short Ws[3 * 16 * 1032];   // 99072 B: [g][jj][k] stride 1032
  __shared__ short Hs[2 * 64 * 136];    // 34816 B: two chunk slots [64][136]
  __shared__ unsigned sbits[64][4];     // starts bitmask: 64 rows x 128 bits
  const int tid  = threadIdx.x;
  const int wg   = blockIdx.x;
  const int jb   = wg & 63, bb = wg >> 6;
  const int j0   = jb * 16, b0 = bb * 64;
  const int wave = tid >> 6, lane = tid & 63;
  const int quad = lane >> 4, l15 = lane & 15;

  // one-time: W_hh slice -> LDS (48 rows x 1024 k)
  for (int c = tid; c < 48 * 128; c += 256) {
    const int row = c >> 7;          // g*16 + jj
    const int kc  = (c & 127) * 8;
    const int g = row >> 4, jj = row & 15;
    *(uint4*)&Ws[row * 1032 + kc] =
        *(const uint4*)(Whh + (size_t)(g * H_ + j0 + jj) * H_ + kc);
  }
  // one-time: starts -> bitmask
  for (int c = tid; c < 64 * 4; c += 256) {
    const int row = c >> 2, w = c & 3;
    unsigned m = 0;
    #pragma unroll
    for (int bi = 0; bi < 32; bi++)
      m |= (starts[(b0 + row) * T_ + w * 32 + bi] ? 1u : 0u) << bi;
    sbits[row][w] = m;
  }
  const float br = bf2f(bhh[j0 + l15]);
  const float bz = bf2f(bhh[H_ + j0 + l15]);
  const float bn = bf2f(bhh[2 * H_ + j0 + l15]);
  const int col = j0 + l15;

  // register-resident fp32 h: 4 owned slots (rows r0..r0+3, col)
  const int r0 = wave * 16 + quad * 4;
  float hreg[4];
  #pragma unroll
  for (int r = 0; r < 4; r++)
    hreg[r] = hf[(size_t)(b0 + r0 + r) * H_ + col];

  // staging thread map (v1): c = tid + u*256 -> row = srow0 + u*8, ull col scol
  const int srow0 = tid >> 5;              // 0..7
  const int scol  = tid & 31;              // ull within 128-col chunk
  const size_t hbg = (size_t)(b0 + srow0) * 256 + scol;  // 256 ull per h row
  const int hsW = srow0 * 136 + scol * 4;  // shorts (8B-aligned)
  const int hsR = (wave * 16 + l15) * 136 + quad * 8;
  const short* wsb = &Ws[l15 * 1032 + quad * 8];

  __syncthreads();  // Ws / sbits ready

// issue the 8 LLC loads (8B each) for chunk ch into dst[8]
#define GRU_LOADC(dst, ch)                                                    \
  { _Pragma("unroll")                                                         \
    for (int u = 0; u < 8; u++)                                               \
      dst[u] = __hip_atomic_load(hin + hbg + u * 2048 + (ch) * 32,            \
                                 __ATOMIC_RELAXED, __HIP_MEMORY_SCOPE_AGENT); }

// masked ds_write of one staged chunk into slot s
#define GRU_WRITE(src, s)                                                     \
  { _Pragma("unroll")                                                         \
    for (int u = 0; u < 8; u++) {                                             \
      ull v = src[u];                                                         \
      if ((sbits[srow0 + u * 8][tw] >> tb) & 1u) v = 0ull;                    \
      *(ull*)&Hs[(s) * 8704 + hsW + u * 1088] = v;                            \
    } }

// 24 MFMAs consuming slots 0 (chunk 2p) and 1 (chunk 2p+1)
#define GRU_MFMA2(p)                                                          \
  { _Pragma("unroll")                                                         \
    for (int w4 = 0; w4 < 4; w4++) {                                          \
      const bf16x8 a = *(const bf16x8*)&Hs[hsR + w4 * 32];                    \
      acc[0] = __builtin_amdgcn_mfma_f32_16x16x32_bf16(                       \
          a, *(const bf16x8*)(wsb + 0 * 16512 + ((2*(p))*4 + w4) * 32),       \
          acc[0], 0, 0, 0);                                                   \
      acc[1] = __builtin_amdgcn_mfma_f32_16x16x32_bf16(                       \
          a, *(const bf16x8*)(wsb + 1 * 16512 + ((2*(p))*4 + w4) * 32),       \
          acc[1], 0, 0, 0);                                                   \
      acc[2] = __builtin_amdgcn_mfma_f32_16x16x32_bf16(                       \
          a, *(const bf16x8*)(wsb + 2 * 16512 + ((2*(p))*4 + w4) * 32),       \
          acc[2], 0, 0, 0);                                                   \
    }                                                                         \
    _Pragma("unroll")                                                         \
    for (int w4 = 0; w4 < 4; w4++) {                                          \
      const bf16x8 a = *(const bf16x8*)&Hs[8704 + hsR + w4 * 32];             \
      acc[0] = __builtin_amdgcn_mfma_f32_16x16x32_bf16(                       \
          a, *(const bf16x8*)(wsb + 0 * 16512 + ((2*(p)+1)*4 + w4) * 32),     \
          acc[0], 0, 0, 0);                                                   \
      acc[1] = __builtin_amdgcn_mfma_f32_16x16x32_bf16(                       \
          a, *(const bf16x8*)(wsb + 1 * 16512 + ((2*(p)+1)*4 + w4) * 32),     \
          acc[1], 0, 0, 0);                                                   \
      acc[2] = __builtin_amdgcn_mfma_f32_16x16x32_bf16(                       \
          a, *(const bf16x8*)(wsb + 2 * 16512 + ((2*(p)+1)*4 + w4) * 32),     \
          acc[2], 0, 0, 0);                                                   \
    } }

  for (int tl = 0; tl < Tc; tl++) {
    const int t = t0 + tl;
    const ull* hin = (t & 1) ? hb1 : hb0;
    unsigned* hout_u = (unsigned*)((t & 1) ? hb0 : hb1);
    const unsigned tw = (unsigned)(t >> 5), tb = (unsigned)(t & 31);

    // 2-chunk-deep LLC prefetch into registers
    ull pf0[8], pf1[8];
    GRU_LOADC(pf0, 0)
    GRU_LOADC(pf1, 1)

    // this step's xg values (12 scalar loads, consumed in epilogue)
    float xr[4], xz[4], xnv[4];
    #pragma unroll
    for (int r = 0; r < 4; r++) {
      const size_t xrow = ((size_t)(b0 + r0 + r) * Tc + tl) * (3 * H_);
      xr[r]  = bf2f(xg[xrow + col]);
      xz[r]  = bf2f(xg[xrow + H_ + col]);
      xnv[r] = bf2f(xg[xrow + 2 * H_ + col]);
    }

    f32x4 acc[3] = {};
    // pair 0: chunks 0,1 ; prefetch 2,3
    __syncthreads();
    GRU_WRITE(pf0, 0) GRU_WRITE(pf1, 1)
    __syncthreads();
    GRU_LOADC(pf0, 2) GRU_LOADC(pf1, 3)
    GRU_MFMA2(0)
    // pair 1: chunks 2,3 ; prefetch 4,5
    __syncthreads();
    GRU_WRITE(pf0, 0) GRU_WRITE(pf1, 1)
    __syncthreads();
    GRU_LOADC(pf0, 4) GRU_LOADC(pf1, 5)
    GRU_MFMA2(1)
    // pair 2: chunks 4,5 ; prefetch 6,7
    __syncthreads();
    GRU_WRITE(pf0, 0) GRU_WRITE(pf1, 1)
    __syncthreads();
    GRU_LOADC(pf0, 6) GRU_LOADC(pf1, 7)
    GRU_MFMA2(2)
    // pair 3: chunks 6,7
    __syncthreads();
    GRU_WRITE(pf0, 0) GRU_WRITE(pf1, 1)
    __syncthreads();
    GRU_MFMA2(3)

    // epilogue: gate math in registers; pack col pairs; atomic store to LLC
    #pragma unroll
    for (int r = 0; r < 4; r++) {
      const int lrow = r0 + r;
      const int b = b0 + lrow;
      const float kb = ((sbits[lrow][tw] >> tb) & 1u) ? 0.0f : 1.0f;
      const float hr = acc[0][r] + br;
      const float hz = acc[1][r] + bz;
      const float hn = acc[2][r] + bn;
      const float rg = 1.0f / (1.0f + __expf(-(xr[r] + hr)));
      const float zg = 1.0f / (1.0f + __expf(-(xz[r] + hz)));
      const float ng = tanhf(xnv[r] + rg * hn);
      const float hv = (1.0f - zg) * ng + zg * (hreg[r] * kb);
      hreg[r] = hv;
      const unsigned mine = (unsigned)f2bf(hv);
      const unsigned other = (unsigned)__shfl_xor((int)mine, 1, 64);
      if ((l15 & 1) == 0) {
        const unsigned packed = mine | (other << 16);
        __hip_atomic_store(&hout_u[((size_t)b * H_ + col) >> 1], packed,
                           __ATOMIC_RELAXED, __HIP_MEMORY_SCOPE_AGENT);
        ((unsigned*)hall)[(((size_t)b * Tc + tl) * H_ + col) >> 1] = packed;
      }
    }

    // fence-free barrier: drain own stores, join, store flag, poll group
    const int my = t0 + tl + 1;
    __builtin_amdgcn_s_waitcnt(0);  // this wave's atomic stores reached LLC
    __syncthreads();                // all 4 waves drained
    if (tid == 0)
      __hip_atomic_store(&flags[wg * 32], my, __ATOMIC_RELAXED,
                         __HIP_MEMORY_SCOPE_AGENT);
    if (tid < 64) {
      while (__hip_atomic_load(&flags[(bb * 64 + tid) * 32], __ATOMIC_RELAXED,
                               __HIP_MEMORY_SCOPE_AGENT) < my)
        __builtin_amdgcn_s_sleep(1);
    }
    __syncthreads();
  }
#undef GRU_LOADC
#undef GRU_WRITE
#undef GRU_MFMA2

  // write back register h to fp32 master (read by next dispatch / hfin_store)
  #pragma unroll
  for (int r = 0; r < 4; r++)
    hf[(size_t)(b0 + r0 + r) * H_ + col] = hreg[r];
}

// ------------- heads: means & log_std fused (N=64), dual-dtype store ---------
__global__ __launch_bounds__(256) void heads_kernel(
    const unsigned short* __restrict__ feats,
    const unsigned short* __restrict__ Wm, const unsigned short* __restrict__ bm,
    const unsigned short* __restrict__ Wl, const unsigned short* __restrict__ bl,
    void* __restrict__ outbuf, int t0, int tcShift, const int* __restrict__ flag)
{
  __shared__ short Fs[64][40];
  __shared__ short Ws[64][40];
  const int fl = *flag;
  const int tid  = threadIdx.x;
  const int wave = tid >> 6, lane = tid & 63;
  const int quad = lane >> 4, l15 = lane & 15;
  const int m0 = blockIdx.x * 64;
  const int lrow = tid >> 2, lk = (tid & 3) * 8;
  f32x4 acc[4] = {};
  for (int k0 = 0; k0 < H_; k0 += 32) {
    __syncthreads();
    *(uint4*)&Fs[lrow][lk] = *(const uint4*)(feats + (size_t)(m0 + lrow) * H_ + k0 + lk);
    const unsigned short* wsrc = (lrow < 32)
        ? (Wm + (size_t)lrow * H_ + k0 + lk)
        : (Wl + (size_t)(lrow - 32) * H_ + k0 + lk);
    *(uint4*)&Ws[lrow][lk] = *(const uint4*)wsrc;
    __syncthreads();
    bf16x8 af = *(const bf16x8*)&Fs[wave * 16 + l15][quad * 8];
    #pragma unroll
    for (int j = 0; j < 4; j++) {
      bf16x8 bfv = *(const bf16x8*)&Ws[j * 16 + l15][quad * 8];
      acc[j] = __builtin_amdgcn_mfma_f32_16x16x32_bf16(af, bfv, acc[j], 0, 0, 0);
    }
  }
  const int tcMask = (1 << tcShift) - 1;
  const size_t lstdBase = (size_t)B_ * T_ * A_;
  #pragma unroll
  for (int j = 0; j < 4; j++) {
    const int col = j * 16 + l15;
    #pragma unroll
    for (int r = 0; r < 4; r++) {
      const int row = m0 + wave * 16 + quad * 4 + r;  // chunk-local
      const int grow = (row >> tcShift) * T_ + t0 + (row & tcMask);
      float v = acc[j][r];
      size_t idx;
      if (col < 32) {
        v += bf2f(bm[col]);
        idx = (size_t)grow * A_ + col;
      } else {
        v += bf2f(bl[col - 32]);
        v = fminf(fmaxf(v, -20.0f), 2.0f);
        idx = lstdBase + (size_t)grow * A_ + (col - 32);
      }
      if (fl) ((float*)outbuf)[idx] = v;
      else    ((unsigned short*)outbuf)[idx] = f2bf(v);
    }
  }
}

__global__ __launch_bounds__(256) void h0_cast(const void* __restrict__ h0,
                                               float* __restrict__ hf,
                                               unsigned short* __restrict__ hb0,
                                               const int* __restrict__ flag) {
  const int fl = *flag;
  int i = blockIdx.x * 256 + threadIdx.x;
  float v = fl ? ((const float*)h0)[i] : bf2f(((const unsigned short*)h0)[i]);
  hf[i] = v;
  hb0[i] = f2bf(v);
}
__global__ __launch_bounds__(256) void hfin_store(const float* __restrict__ h,
                                                  void* __restrict__ outbuf,
                                                  const int* __restrict__ flag) {
  const int fl = *flag;
  const size_t base = 2ull * B_ * T_ * A_;
  int i = blockIdx.x * 256 + threadIdx.x;
  if (fl) ((float*)outbuf)[base + i] = h[i];
  else    ((unsigned short*)outbuf)[base + i] = f2bf(h[i]);
}

extern "C" void kernel_launch(void* const* d_in, const int* in_sizes, int n_in,
                              void* d_out, int out_size, void* d_ws, size_t ws_size,
                              hipStream_t stream)
{
  const void* obs    = d_in[0];
  const void* h0in   = d_in[1];
  const int*  starts = (const int*)d_in[2];
  const void* fsrc[14] = { d_in[5], d_in[7], d_in[9], d_in[11], d_in[13], d_in[15],
                           d_in[3], d_in[4], d_in[6], d_in[8], d_in[10], d_in[12],
                           d_in[14], d_in[16] };
  const int fn[14] = { FC_ * D_, 3 * H_ * FC_, 3 * H_ * H_, H_ * H_, A_ * H_, A_ * H_,
                       D_, D_, FC_, 3 * H_, 3 * H_, H_, A_, A_ };

  char* ws = (char*)d_ws;
  int* flag = (int*)ws;
  size_t cur = 256;
  unsigned short* cdst[14];
  for (int i = 0; i < 14; i++) {
    cdst[i] = (unsigned short*)(ws + cur);
    cur += (size_t)fn[i] * 2;
    cur = (cur + 255) & ~255ull;
  }
  const size_t chunkBase = cur;
  const size_t fixedTail = 1048576ull /*hf*/ + 2ull * 524288ull /*hb0/1*/
                         + 32768ull /*flags*/;

  // Pick largest Tc with: chunkBase + Tc*2883584 + fixedTail <= ws_size
  int Tc = 1;
  for (int c = 32; c >= 1; c >>= 1) {
    size_t need = chunkBase + (size_t)c * 2883584ull + fixedTail;
    if (need <= ws_size) { Tc = c; break; }
  }
  int tcShift = 0;
  while ((1 << tcShift) < Tc) tcShift++;

  unsigned short* xn   = (unsigned short*)(ws + chunkBase);
  unsigned short* xfc  = (unsigned short*)(ws + chunkBase + (size_t)Tc * 262144ull);
  unsigned short* xg   = (unsigned short*)(ws + chunkBase + (size_t)Tc * 786432ull);
  unsigned short* hall = (unsigned short*)(ws + chunkBase + (size_t)Tc * 2359296ull);
  size_t o = chunkBase + (size_t)Tc * 2883584ull;
  float* hf           = (float*)(ws + o);           o += 1048576ull;
  unsigned short* hb0 = (unsigned short*)(ws + o);  o += 524288ull;
  unsigned short* hb1 = (unsigned short*)(ws + o);  o += 524288ull;
  int* flags          = (int*)(ws + o);             // NWG_ x 128B
  unsigned short* feats = xg;  // xg dead once the chunk's scan is done

  const unsigned short *Wfc = cdst[0], *Wih = cdst[1], *Whh = cdst[2], *Wout = cdst[3];
  const unsigned short *Wmean = cdst[4], *Wls = cdst[5];
  const unsigned short *gam = cdst[6], *bet = cdst[7], *bfc = cdst[8], *bih = cdst[9];
  const unsigned short *bhh = cdst[10], *bout = cdst[11], *bmean = cdst[12], *bls = cdst[13];

  detect_kernel<<<dim3(1), dim3(256), 0, stream>>>((const unsigned short*)obs, flag);
  CanonArgs ca;
  int total = 0;
  for (int i = 0; i < 14; i++) {
    ca.src[i] = fsrc[i];
    ca.dst[i] = cdst[i];
    ca.ofs[i] = total;
    total += fn[i];
  }
  ca.ofs[14] = total;
  canon_kernel<<<dim3((total / 8 + 255) / 256), dim3(256), 0, stream>>>(ca, flag);
  h0_cast<<<dim3(B_ * H_ / 256), dim3(256), 0, stream>>>(h0in, hf, hb0, flag);
  hipMemsetAsync(flags, 0, 32768, stream);

  const int Mc = B_ * Tc;
  for (int t0 = 0; t0 < T_; t0 += Tc) {
    ln_kernel<<<dim3(Mc / 4), dim3(256), 0, stream>>>(obs, gam, bet, xn, t0, tcShift, flag);
    gemm_tn<<<dim3(FC_ / 128, Mc / 128), dim3(256), 0, stream>>>(
        xn, Wfc, bfc, xfc, Mc, FC_, D_, 1);
    gemm_tn<<<dim3(3 * H_ / 128, Mc / 128), dim3(256), 0, stream>>>(
        xfc, Wih, bih, xg, Mc, 3 * H_, FC_, 0);

    gru_scan<<<dim3(NWG_), dim3(256), 0, stream>>>(
        xg, starts, Whh, bhh, hf,
        (ull*)hb0, (ull*)hb1,
        hall, t0, Tc, flags);

    gemm_tn<<<dim3(H_ / 128, Mc / 128), dim3(256), 0, stream>>>(
        hall, Wout, bout, feats, Mc, H_, H_, 1);
    heads_kernel<<<dim3(Mc / 64), dim3(256), 0, stream>>>(
        feats, Wmean, bmean, Wls, bls, d_out, t0, tcShift, flag);
  }

  hfin_store<<<dim3(B_ * H_ / 256), dim3(256), 0, stream>>>(hf, d_out, flag);
}

// Round 7
// 1744.810 us; speedup vs baseline: 1.5701x; 1.0227x over previous
//
#include <hip/hip_runtime.h>
#include <hip/hip_bf16.h>

#define B_ 256
#define T_ 128
#define D_ 512
#define H_ 1024
#define FC_ 1024
#define A_ 32
#define NWG_ 256

typedef short bf16x8 __attribute__((ext_vector_type(8)));
typedef float f32x4 __attribute__((ext_vector_type(4)));
typedef unsigned long long ull;

__device__ __forceinline__ float bf2f(unsigned short u) {
  return __uint_as_float(((unsigned)u) << 16);
}
// round-to-nearest-even fp32 -> bf16
__device__ __forceinline__ unsigned short f2bf(float x) {
  unsigned u = __float_as_uint(x);
  u = u + 0x7fffu + ((u >> 16) & 1u);
  return (unsigned short)(u >> 16);
}
__device__ __forceinline__ void unpack8(uint4 v, float* f) {
  f[0] = bf2f(v.x & 0xffff); f[1] = bf2f(v.x >> 16);
  f[2] = bf2f(v.y & 0xffff); f[3] = bf2f(v.y >> 16);
  f[4] = bf2f(v.z & 0xffff); f[5] = bf2f(v.z >> 16);
  f[6] = bf2f(v.w & 0xffff); f[7] = bf2f(v.w >> 16);
}
__device__ __forceinline__ uint4 pack8(const float* f) {
  uint4 v;
  v.x = (unsigned)f2bf(f[0]) | ((unsigned)f2bf(f[1]) << 16);
  v.y = (unsigned)f2bf(f[2]) | ((unsigned)f2bf(f[3]) << 16);
  v.z = (unsigned)f2bf(f[4]) | ((unsigned)f2bf(f[5]) << 16);
  v.w = (unsigned)f2bf(f[6]) | ((unsigned)f2bf(f[7]) << 16);
  return v;
}

// ------------- dtype probe: bf16 inputs -> flag 0, fp32 inputs -> flag 1 -----
__global__ __launch_bounds__(256) void detect_kernel(
    const unsigned short* __restrict__ obs, int* __restrict__ flag)
{
  __shared__ int cnt;
  if (threadIdx.x == 0) cnt = 0;
  __syncthreads();
  int c = 0;
  for (int i = threadIdx.x; i < 8192; i += 256) {
    unsigned e = (obs[i] >> 7) & 0xffu;  // bf16 exponent field
    if (e >= 0x86u) c++;
  }
  atomicAdd(&cnt, c);
  __syncthreads();
  if (threadIdx.x == 0) *flag = (cnt >= 64) ? 1 : 0;
}

// ------------- canonicalize 14 float tensors to bf16 workspace copies -------
struct CanonArgs {
  const void* src[14];
  unsigned short* dst[14];
  int ofs[15];  // cumulative element offsets (all multiples of 8)
};
__global__ __launch_bounds__(256) void canon_kernel(CanonArgs a,
                                                    const int* __restrict__ flag)
{
  const int fl = *flag;
  const int i0 = (blockIdx.x * 256 + threadIdx.x) * 8;
  int t = 0;
  while (t < 14 && i0 >= a.ofs[t + 1]) t++;
  if (t >= 14) return;
  const int local = i0 - a.ofs[t];
  unsigned short* d = a.dst[t] + local;
  if (fl) {
    const float* s = (const float*)a.src[t] + local;
    #pragma unroll
    for (int e = 0; e < 8; e++) d[e] = f2bf(s[e]);
  } else {
    const unsigned short* s = (const unsigned short*)a.src[t] + local;
    #pragma unroll
    for (int e = 0; e < 8; e++) d[e] = s[e];
  }
}

// ---------------- LayerNorm: one wave per row of D=512 (chunked over t) ------
__global__ __launch_bounds__(256) void ln_kernel(
    const void* __restrict__ obs,
    const unsigned short* __restrict__ gamma_,
    const unsigned short* __restrict__ beta_,
    unsigned short* __restrict__ xn, int t0, int tcShift,
    const int* __restrict__ flag)
{
  const int fl = *flag;
  const int lane = threadIdx.x & 63;
  const int rloc = blockIdx.x * 4 + (threadIdx.x >> 6);
  const int b  = rloc >> tcShift;
  const int tl = rloc & ((1 << tcShift) - 1);
  const int grow = b * T_ + t0 + tl;
  float f[8];
  if (fl) {
    const float* of = (const float*)obs + (size_t)grow * D_ + lane * 8;
    const float4 v0 = *(const float4*)of;
    const float4 v1 = *(const float4*)(of + 4);
    f[0] = v0.x; f[1] = v0.y; f[2] = v0.z; f[3] = v0.w;
    f[4] = v1.x; f[5] = v1.y; f[6] = v1.z; f[7] = v1.w;
  } else {
    uint4 v = *(const uint4*)((const unsigned short*)obs + (size_t)grow * D_ + lane * 8);
    unpack8(v, f);
  }
  float s = 0.f, ss = 0.f;
  #pragma unroll
  for (int i = 0; i < 8; i++) { s += f[i]; ss += f[i] * f[i]; }
  #pragma unroll
  for (int off = 32; off > 0; off >>= 1) {
    s  += __shfl_xor(s,  off, 64);
    ss += __shfl_xor(ss, off, 64);
  }
  const float mu  = s * (1.0f / D_);
  const float var = ss * (1.0f / D_) - mu * mu;
  const float inv = rsqrtf(var + 1e-5f);
  float g[8], b8[8];
  unpack8(*(const uint4*)(gamma_ + lane * 8), g);
  unpack8(*(const uint4*)(beta_  + lane * 8), b8);
  float o[8];
  #pragma unroll
  for (int i = 0; i < 8; i++) o[i] = (f[i] - mu) * inv * g[i] + b8[i];
  *(uint4*)(xn + (size_t)rloc * D_ + lane * 8) = pack8(o);
}

// ------------- generic TN GEMM: C[M,N] = A[M,K] * B[N,K]^T + bias -------------
// m97 structure: 128x128 tile, BK=32, linear LDS, global_load_lds width=16,
// 2-barrier K-loop. Staging never touches VGPRs.
__global__ __launch_bounds__(256) void gemm_tn(
    const unsigned short* __restrict__ A, const unsigned short* __restrict__ Bm,
    const unsigned short* __restrict__ bias, unsigned short* __restrict__ C,
    int M, int N, int K, int relu)
{
  __shared__ short As[128 * 32];   // [row][k] linear, 8KB
  __shared__ short Bs[128 * 32];
  const int tid  = threadIdx.x;
  const int wave = tid >> 6, lane = tid & 63;
  const int quad = lane >> 4, l15 = lane & 15;
  const int m0 = blockIdx.y * 128, n0 = blockIdx.x * 128;
  const int wm = (wave >> 1) * 64, wn = (wave & 1) * 64;
  const int srow = tid >> 2;          // 0..63
  const int skc  = (tid & 3) * 8;     // shorts
  const size_t aoff0 = (size_t)(m0 + srow) * K + skc;
  const size_t aoff1 = (size_t)(m0 + 64 + srow) * K + skc;
  const size_t boff0 = (size_t)(n0 + srow) * K + skc;
  const size_t boff1 = (size_t)(n0 + 64 + srow) * K + skc;
  const int lb0 = wave * 512;          // shorts
  const int lb1 = 2048 + wave * 512;
  f32x4 acc[4][4] = {};
  for (int k0 = 0; k0 < K; k0 += 32) {
    __syncthreads();
    __builtin_amdgcn_global_load_lds(
        (const __attribute__((address_space(1))) unsigned*)(A + aoff0 + k0),
        (__attribute__((address_space(3))) unsigned*)&As[lb0], 16, 0, 0);
    __builtin_amdgcn_global_load_lds(
        (const __attribute__((address_space(1))) unsigned*)(A + aoff1 + k0),
        (__attribute__((address_space(3))) unsigned*)&As[lb1], 16, 0, 0);
    __builtin_amdgcn_global_load_lds(
        (const __attribute__((address_space(1))) unsigned*)(Bm + boff0 + k0),
        (__attribute__((address_space(3))) unsigned*)&Bs[lb0], 16, 0, 0);
    __builtin_amdgcn_global_load_lds(
        (const __attribute__((address_space(1))) unsigned*)(Bm + boff1 + k0),
        (__attribute__((address_space(3))) unsigned*)&Bs[lb1], 16, 0, 0);
    __syncthreads();  // compiler drains vmcnt before barrier
    bf16x8 af[4], bfv[4];
    #pragma unroll
    for (int i = 0; i < 4; i++) af[i]  = *(const bf16x8*)&As[(wm + i * 16 + l15) * 32 + quad * 8];
    #pragma unroll
    for (int j = 0; j < 4; j++) bfv[j] = *(const bf16x8*)&Bs[(wn + j * 16 + l15) * 32 + quad * 8];
    #pragma unroll
    for (int i = 0; i < 4; i++)
      #pragma unroll
      for (int j = 0; j < 4; j++)
        acc[i][j] = __builtin_amdgcn_mfma_f32_16x16x32_bf16(af[i], bfv[j], acc[i][j], 0, 0, 0);
  }
  #pragma unroll
  for (int j = 0; j < 4; j++) {
    const int col = n0 + wn + j * 16 + l15;
    const float bj = bias ? bf2f(bias[col]) : 0.0f;
    #pragma unroll
    for (int i = 0; i < 4; i++) {
      const int row = m0 + wm + i * 16 + quad * 4;
      #pragma unroll
      for (int r = 0; r < 4; r++) {
        float v = acc[i][j][r] + bj;
        if (relu) v = fmaxf(v, 0.0f);
        C[(size_t)(row + r) * N + col] = f2bf(v);
      }
    }
  }
}

// ---------------- persistent GRU scan (fence-free LLC protocol) --------------
// 256 WGs (1/CU). WG = (bb,jb): bb owns 64 batches, jb owns 16 cols x 3 gates.
// W_hh slice (96KB) + starts bitmask in LDS once. h fp32 in registers.
// v8 = v7 with RAW inner barriers + true 4-deep prefetch:
//  * __syncthreads drains vmcnt(0) before s_barrier (guide §5) -- v7's 8 inner
//    barriers killed any prefetch crossing them. Replace with raw
//    __builtin_amdgcn_s_barrier() fenced by sched_barrier(0), plus explicit
//    "s_waitcnt lgkmcnt(0)" (+sched_barrier, rule #18) after ds_writes for
//    cross-wave LDS visibility. vmem loads now stay in flight across barriers.
//  * pfA/pfB hold 4 chunks (64 VGPRs). pfA reloaded at pair 0 (chunks 4,5),
//    consumed at pair 2; pfB reloaded at pair 1 (6,7), consumed at pair 3.
//    Every WRITE except pair 0's (serial h dependency) has >=800cy cover.
//  * Flag barrier keeps __syncthreads (protocol requires the drain).
__global__ __launch_bounds__(256, 1) void gru_scan(
    const unsigned short* __restrict__ xg,   // chunk-local [B][Tc][3H]
    const int* __restrict__ starts,
    const unsigned short* __restrict__ Whh,
    const unsigned short* __restrict__ bhh,
    float* __restrict__ hf,                  // [B][H] fp32 master
    ull* __restrict__ hb0,                   // bf16 mirror ping (8B units)
    ull* __restrict__ hb1,                   // bf16 mirror pong
    unsigned short* __restrict__ hall,       // [B][Tc][H] bf16
    int t0, int Tc,
    int* __restrict__ flags)                 // [NWG_] step flags, 128B stride
{
  __shared__ short Ws[3 * 16 * 1032];   // 99072 B: [g][jj][k] stride 1032
  __shared__ short Hs[2 * 64 * 136];    // 34816 B: two chunk slots [64][136]
  __shared__ unsigned sbits[64][4];     // starts bitmask: 64 rows x 128 bits
  const int tid  = threadIdx.x;
  const int wg   = blockIdx.x;
  const int jb   = wg & 63, bb = wg >> 6;
  const int j0   = jb * 16, b0 = bb * 64;
  const int wave = tid >> 6, lane = tid & 63;
  const int quad = lane >> 4, l15 = lane & 15;

  // one-time: W_hh slice -> LDS (48 rows x 1024 k)
  for (int c = tid; c < 48 * 128; c += 256) {
    const int row = c >> 7;          // g*16 + jj
    const int kc  = (c & 127) * 8;
    const int g = row >> 4, jj = row & 15;
    *(uint4*)&Ws[row * 1032 + kc] =
        *(const uint4*)(Whh + (size_t)(g * H_ + j0 + jj) * H_ + kc);
  }
  // one-time: starts -> bitmask
  for (int c = tid; c < 64 * 4; c += 256) {
    const int row = c >> 2, w = c & 3;
    unsigned m = 0;
    #pragma unroll
    for (int bi = 0; bi < 32; bi++)
      m |= (starts[(b0 + row) * T_ + w * 32 + bi] ? 1u : 0u) << bi;
    sbits[row][w] = m;
  }
  const float br = bf2f(bhh[j0 + l15]);
  const float bz = bf2f(bhh[H_ + j0 + l15]);
  const float bn = bf2f(bhh[2 * H_ + j0 + l15]);
  const int col = j0 + l15;

  // register-resident fp32 h: 4 owned slots (rows r0..r0+3, col)
  const int r0 = wave * 16 + quad * 4;
  float hreg[4];
  #pragma unroll
  for (int r = 0; r < 4; r++)
    hreg[r] = hf[(size_t)(b0 + r0 + r) * H_ + col];

  // staging thread map (v1): c = tid + u*256 -> row = srow0 + u*8, ull col scol
  const int srow0 = tid >> 5;              // 0..7
  const int scol  = tid & 31;              // ull within 128-col chunk
  const size_t hbg = (size_t)(b0 + srow0) * 256 + scol;  // 256 ull per h row
  const int hsW = srow0 * 136 + scol * 4;  // shorts (8B-aligned)
  const int hsR = (wave * 16 + l15) * 136 + quad * 8;
  const short* wsb = &Ws[l15 * 1032 + quad * 8];

  __syncthreads();  // Ws / sbits ready

// raw workgroup barrier: no vmcnt drain; sched_barrier pins ds ops around it
#define GRU_RBAR                                                              \
  { __builtin_amdgcn_sched_barrier(0); __builtin_amdgcn_s_barrier();          \
    __builtin_amdgcn_sched_barrier(0); }
// ds_write completion fence (rule #18: sched_barrier after inline-asm wait)
#define GRU_LGKM0                                                             \
  { asm volatile("s_waitcnt lgkmcnt(0)" ::: "memory");                        \
    __builtin_amdgcn_sched_barrier(0); }

// issue the 8 LLC loads (8B each) for chunk ch into dst[8]
#define GRU_LOADC(dst, ch)                                                    \
  { _Pragma("unroll")                                                         \
    for (int u = 0; u < 8; u++)                                               \
      dst[u] = __hip_atomic_load(hin + hbg + u * 2048 + (ch) * 32,            \
                                 __ATOMIC_RELAXED, __HIP_MEMORY_SCOPE_AGENT); }

// masked ds_write of one staged chunk into slot s
#define GRU_WRITE(src, s)                                                     \
  { _Pragma("unroll")                                                         \
    for (int u = 0; u < 8; u++) {                                             \
      ull v = src[u];                                                         \
      if ((sbits[srow0 + u * 8][tw] >> tb) & 1u) v = 0ull;                    \
      *(ull*)&Hs[(s) * 8704 + hsW + u * 1088] = v;                            \
    } }

// 24 MFMAs consuming slots 0 (chunk 2p) and 1 (chunk 2p+1)
#define GRU_MFMA2(p)                                                          \
  { _Pragma("unroll")                                                         \
    for (int w4 = 0; w4 < 4; w4++) {                                          \
      const bf16x8 a = *(const bf16x8*)&Hs[hsR + w4 * 32];                    \
      acc[0] = __builtin_amdgcn_mfma_f32_16x16x32_bf16(                       \
          a, *(const bf16x8*)(wsb + 0 * 16512 + ((2*(p))*4 + w4) * 32),       \
          acc[0], 0, 0, 0);                                                   \
      acc[1] = __builtin_amdgcn_mfma_f32_16x16x32_bf16(                       \
          a, *(const bf16x8*)(wsb + 1 * 16512 + ((2*(p))*4 + w4) * 32),       \
          acc[1], 0, 0, 0);                                                   \
      acc[2] = __builtin_amdgcn_mfma_f32_16x16x32_bf16(                       \
          a, *(const bf16x8*)(wsb + 2 * 16512 + ((2*(p))*4 + w4) * 32),       \
          acc[2], 0, 0, 0);                                                   \
    }                                                                         \
    _Pragma("unroll")                                                         \
    for (int w4 = 0; w4 < 4; w4++) {                                          \
      const bf16x8 a = *(const bf16x8*)&Hs[8704 + hsR + w4 * 32];             \
      acc[0] = __builtin_amdgcn_mfma_f32_16x16x32_bf16(                       \
          a, *(const bf16x8*)(wsb + 0 * 16512 + ((2*(p)+1)*4 + w4) * 32),     \
          acc[0], 0, 0, 0);                                                   \
      acc[1] = __builtin_amdgcn_mfma_f32_16x16x32_bf16(                       \
          a, *(const bf16x8*)(wsb + 1 * 16512 + ((2*(p)+1)*4 + w4) * 32),     \
          acc[1], 0, 0, 0);                                                   \
      acc[2] = __builtin_amdgcn_mfma_f32_16x16x32_bf16(                       \
          a, *(const bf16x8*)(wsb + 2 * 16512 + ((2*(p)+1)*4 + w4) * 32),     \
          acc[2], 0, 0, 0);                                                   \
    } }

  for (int tl = 0; tl < Tc; tl++) {
    const int t = t0 + tl;
    const ull* hin = (t & 1) ? hb1 : hb0;
    unsigned* hout_u = (unsigned*)((t & 1) ? hb0 : hb1);
    const unsigned tw = (unsigned)(t >> 5), tb = (unsigned)(t & 31);

    // 4-chunk-deep LLC prefetch into registers (flows across raw barriers)
    ull pfA0[8], pfA1[8], pfB0[8], pfB1[8];
    GRU_LOADC(pfA0, 0) GRU_LOADC(pfA1, 1)
    GRU_LOADC(pfB0, 2) GRU_LOADC(pfB1, 3)

    // this step's xg values (12 scalar loads, consumed in epilogue)
    float xr[4], xz[4], xnv[4];
    #pragma unroll
    for (int r = 0; r < 4; r++) {
      const size_t xrow = ((size_t)(b0 + r0 + r) * Tc + tl) * (3 * H_);
      xr[r]  = bf2f(xg[xrow + col]);
      xz[r]  = bf2f(xg[xrow + H_ + col]);
      xnv[r] = bf2f(xg[xrow + 2 * H_ + col]);
    }

    f32x4 acc[3] = {};
    // pair 0: write chunks 0,1 (serial-dep wait); reload pfA <- 4,5
    GRU_WRITE(pfA0, 0) GRU_WRITE(pfA1, 1)
    GRU_LGKM0
    GRU_RBAR
    GRU_LOADC(pfA0, 4) GRU_LOADC(pfA1, 5)
    GRU_MFMA2(0)
    // pair 1: chunks 2,3 (loaded at step top); reload pfB <- 6,7
    GRU_RBAR
    GRU_WRITE(pfB0, 0) GRU_WRITE(pfB1, 1)
    GRU_LGKM0
    GRU_RBAR
    GRU_LOADC(pfB0, 6) GRU_LOADC(pfB1, 7)
    GRU_MFMA2(1)
    // pair 2: chunks 4,5 (issued at pair 0)
    GRU_RBAR
    GRU_WRITE(pfA0, 0) GRU_WRITE(pfA1, 1)
    GRU_LGKM0
    GRU_RBAR
    GRU_MFMA2(2)
    // pair 3: chunks 6,7 (issued at pair 1)
    GRU_RBAR
    GRU_WRITE(pfB0, 0) GRU_WRITE(pfB1, 1)
    GRU_LGKM0
    GRU_RBAR
    GRU_MFMA2(3)

    // epilogue: gate math in registers; pack col pairs; atomic store to LLC
    #pragma unroll
    for (int r = 0; r < 4; r++) {
      const int lrow = r0 + r;
      const int b = b0 + lrow;
      const float kb = ((sbits[lrow][tw] >> tb) & 1u) ? 0.0f : 1.0f;
      const float hr = acc[0][r] + br;
      const float hz = acc[1][r] + bz;
      const float hn = acc[2][r] + bn;
      const float rg = 1.0f / (1.0f + __expf(-(xr[r] + hr)));
      const float zg = 1.0f / (1.0f + __expf(-(xz[r] + hz)));
      const float ng = tanhf(xnv[r] + rg * hn);
      const float hv = (1.0f - zg) * ng + zg * (hreg[r] * kb);
      hreg[r] = hv;
      const unsigned mine = (unsigned)f2bf(hv);
      const unsigned other = (unsigned)__shfl_xor((int)mine, 1, 64);
      if ((l15 & 1) == 0) {
        const unsigned packed = mine | (other << 16);
        __hip_atomic_store(&hout_u[((size_t)b * H_ + col) >> 1], packed,
                           __ATOMIC_RELAXED, __HIP_MEMORY_SCOPE_AGENT);
        ((unsigned*)hall)[(((size_t)b * Tc + tl) * H_ + col) >> 1] = packed;
      }
    }

    // fence-free barrier: drain own stores, join, store flag, poll group
    const int my = t0 + tl + 1;
    __builtin_amdgcn_s_waitcnt(0);  // this wave's atomic stores reached LLC
    __syncthreads();                // all 4 waves drained
    if (tid == 0)
      __hip_atomic_store(&flags[wg * 32], my, __ATOMIC_RELAXED,
                         __HIP_MEMORY_SCOPE_AGENT);
    if (tid < 64) {
      while (__hip_atomic_load(&flags[(bb * 64 + tid) * 32], __ATOMIC_RELAXED,
                               __HIP_MEMORY_SCOPE_AGENT) < my)
        __builtin_amdgcn_s_sleep(1);
    }
    __syncthreads();
  }
#undef GRU_LOADC
#undef GRU_WRITE
#undef GRU_MFMA2
#undef GRU_RBAR
#undef GRU_LGKM0

  // write back register h to fp32 master (read by next dispatch / hfin_store)
  #pragma unroll
  for (int r = 0; r < 4; r++)
    hf[(size_t)(b0 + r0 + r) * H_ + col] = hreg[r];
}

// ------------- heads: means & log_std fused (N=64), dual-dtype store ---------
__global__ __launch_bounds__(256) void heads_kernel(
    const unsigned short* __restrict__ feats,
    const unsigned short* __restrict__ Wm, const unsigned short* __restrict__ bm,
    const unsigned short* __restrict__ Wl, const unsigned short* __restrict__ bl,
    void* __restrict__ outbuf, int t0, int tcShift, const int* __restrict__ flag)
{
  __shared__ short Fs[64][40];
  __shared__ short Ws[64][40];
  const int fl = *flag;
  const int tid  = threadIdx.x;
  const int wave = tid >> 6, lane = tid & 63;
  const int quad = lane >> 4, l15 = lane & 15;
  const int m0 = blockIdx.x * 64;
  const int lrow = tid >> 2, lk = (tid & 3) * 8;
  f32x4 acc[4] = {};
  for (int k0 = 0; k0 < H_; k0 += 32) {
    __syncthreads();
    *(uint4*)&Fs[lrow][lk] = *(const uint4*)(feats + (size_t)(m0 + lrow) * H_ + k0 + lk);
    const unsigned short* wsrc = (lrow < 32)
        ? (Wm + (size_t)lrow * H_ + k0 + lk)
        : (Wl + (size_t)(lrow - 32) * H_ + k0 + lk);
    *(uint4*)&Ws[lrow][lk] = *(const uint4*)wsrc;
    __syncthreads();
    bf16x8 af = *(const bf16x8*)&Fs[wave * 16 + l15][quad * 8];
    #pragma unroll
    for (int j = 0; j < 4; j++) {
      bf16x8 bfv = *(const bf16x8*)&Ws[j * 16 + l15][quad * 8];
      acc[j] = __builtin_amdgcn_mfma_f32_16x16x32_bf16(af, bfv, acc[j], 0, 0, 0);
    }
  }
  const int tcMask = (1 << tcShift) - 1;
  const size_t lstdBase = (size_t)B_ * T_ * A_;
  #pragma unroll
  for (int j = 0; j < 4; j++) {
    const int col = j * 16 + l15;
    #pragma unroll
    for (int r = 0; r < 4; r++) {
      const int row = m0 + wave * 16 + quad * 4 + r;  // chunk-local
      const int grow = (row >> tcShift) * T_ + t0 + (row & tcMask);
      float v = acc[j][r];
      size_t idx;
      if (col < 32) {
        v += bf2f(bm[col]);
        idx = (size_t)grow * A_ + col;
      } else {
        v += bf2f(bl[col - 32]);
        v = fminf(fmaxf(v, -20.0f), 2.0f);
        idx = lstdBase + (size_t)grow * A_ + (col - 32);
      }
      if (fl) ((float*)outbuf)[idx] = v;
      else    ((unsigned short*)outbuf)[idx] = f2bf(v);
    }
  }
}

__global__ __launch_bounds__(256) void h0_cast(const void* __restrict__ h0,
                                               float* __restrict__ hf,
                                               unsigned short* __restrict__ hb0,
                                               const int* __restrict__ flag) {
  const int fl = *flag;
  int i = blockIdx.x * 256 + threadIdx.x;
  float v = fl ? ((const float*)h0)[i] : bf2f(((const unsigned short*)h0)[i]);
  hf[i] = v;
  hb0[i] = f2bf(v);
}
__global__ __launch_bounds__(256) void hfin_store(const float* __restrict__ h,
                                                  void* __restrict__ outbuf,
                                                  const int* __restrict__ flag) {
  const int fl = *flag;
  const size_t base = 2ull * B_ * T_ * A_;
  int i = blockIdx.x * 256 + threadIdx.x;
  if (fl) ((float*)outbuf)[base + i] = h[i];
  else    ((unsigned short*)outbuf)[base + i] = f2bf(h[i]);
}

extern "C" void kernel_launch(void* const* d_in, const int* in_sizes, int n_in,
                              void* d_out, int out_size, void* d_ws, size_t ws_size,
                              hipStream_t stream)
{
  const void* obs    = d_in[0];
  const void* h0in   = d_in[1];
  const int*  starts = (const int*)d_in[2];
  const void* fsrc[14] = { d_in[5], d_in[7], d_in[9], d_in[11], d_in[13], d_in[15],
                           d_in[3], d_in[4], d_in[6], d_in[8], d_in[10], d_in[12],
                           d_in[14], d_in[16] };
  const int fn[14] = { FC_ * D_, 3 * H_ * FC_, 3 * H_ * H_, H_ * H_, A_ * H_, A_ * H_,
                       D_, D_, FC_, 3 * H_, 3 * H_, H_, A_, A_ };

  char* ws = (char*)d_ws;
  int* flag = (int*)ws;
  size_t cur = 256;
  unsigned short* cdst[14];
  for (int i = 0; i < 14; i++) {
    cdst[i] = (unsigned short*)(ws + cur);
    cur += (size_t)fn[i] * 2;
    cur = (cur + 255) & ~255ull;
  }
  const size_t chunkBase = cur;
  const size_t fixedTail = 1048576ull /*hf*/ + 2ull * 524288ull /*hb0/1*/
                         + 32768ull /*flags*/;

  // Pick largest Tc with: chunkBase + Tc*2883584 + fixedTail <= ws_size
  int Tc = 1;
  for (int c = 32; c >= 1; c >>= 1) {
    size_t need = chunkBase + (size_t)c * 2883584ull + fixedTail;
    if (need <= ws_size) { Tc = c; break; }
  }
  int tcShift = 0;
  while ((1 << tcShift) < Tc) tcShift++;

  unsigned short* xn   = (unsigned short*)(ws + chunkBase);
  unsigned short* xfc  = (unsigned short*)(ws + chunkBase + (size_t)Tc * 262144ull);
  unsigned short* xg   = (unsigned short*)(ws + chunkBase + (size_t)Tc * 786432ull);
  unsigned short* hall = (unsigned short*)(ws + chunkBase + (size_t)Tc * 2359296ull);
  size_t o = chunkBase + (size_t)Tc * 2883584ull;
  float* hf           = (float*)(ws + o);           o += 1048576ull;
  unsigned short* hb0 = (unsigned short*)(ws + o);  o += 524288ull;
  unsigned short* hb1 = (unsigned short*)(ws + o);  o += 524288ull;
  int* flags          = (int*)(ws + o);             // NWG_ x 128B
  unsigned short* feats = xg;  // xg dead once the chunk's scan is done

  const unsigned short *Wfc = cdst[0], *Wih = cdst[1], *Whh = cdst[2], *Wout = cdst[3];
  const unsigned short *Wmean = cdst[4], *Wls = cdst[5];
  const unsigned short *gam = cdst[6], *bet = cdst[7], *bfc = cdst[8], *bih = cdst[9];
  const unsigned short *bhh = cdst[10], *bout = cdst[11], *bmean = cdst[12], *bls = cdst[13];

  detect_kernel<<<dim3(1), dim3(256), 0, stream>>>((const unsigned short*)obs, flag);
  CanonArgs ca;
  int total = 0;
  for (int i = 0; i < 14; i++) {
    ca.src[i] = fsrc[i];
    ca.dst[i] = cdst[i];
    ca.ofs[i] = total;
    total += fn[i];
  }
  ca.ofs[14] = total;
  canon_kernel<<<dim3((total / 8 + 255) / 256), dim3(256), 0, stream>>>(ca, flag);
  h0_cast<<<dim3(B_ * H_ / 256), dim3(256), 0, stream>>>(h0in, hf, hb0, flag);
  hipMemsetAsync(flags, 0, 32768, stream);

  const int Mc = B_ * Tc;
  for (int t0 = 0; t0 < T_; t0 += Tc) {
    ln_kernel<<<dim3(Mc / 4), dim3(256), 0, stream>>>(obs, gam, bet, xn, t0, tcShift, flag);
    gemm_tn<<<dim3(FC_ / 128, Mc / 128), dim3(256), 0, stream>>>(
        xn, Wfc, bfc, xfc, Mc, FC_, D_, 1);
    gemm_tn<<<dim3(3 * H_ / 128, Mc / 128), dim3(256), 0, stream>>>(
        xfc, Wih, bih, xg, Mc, 3 * H_, FC_, 0);

    gru_scan<<<dim3(NWG_), dim3(256), 0, stream>>>(
        xg, starts, Whh, bhh, hf,
        (ull*)hb0, (ull*)hb1,
        hall, t0, Tc, flags);

    gemm_tn<<<dim3(H_ / 128, Mc / 128), dim3(256), 0, stream>>>(
        hall, Wout, bout, feats, Mc, H_, H_, 1);
    heads_kernel<<<dim3(Mc / 64), dim3(256), 0, stream>>>(
        feats, Wmean, bmean, Wls, bls, d_out, t0, tcShift, flag);
  }

  hfin_store<<<dim3(B_ * H_ / 256), dim3(256), 0, stream>>>(hf, d_out, flag);
}